// Round 6
// baseline (1774.797 us; speedup 1.0000x reference)
//
#include <hip/hip_runtime.h>
#include <math.h>

// ---------------- problem constants ----------------
#define POSE_ROWS 144
#define NF 135
#define DD 512
#define KQ 10
#define DCTN 34
#define INN 120
#define OUTN 24
#define VN 87
#define BATCH 256
#define RP 34816              // padded row dim: 256 * 136
#define NODEP 136
#define BN_SCALE 0.9999950000374997f

typedef __attribute__((ext_vector_type(8))) short short8;
typedef __attribute__((ext_vector_type(4))) float floatx4;

static __device__ __forceinline__ ushort f2bf(float f) {
    unsigned u = __builtin_bit_cast(unsigned, f);
    u = (u + 0x7FFFu + ((u >> 16) & 1u)) >> 16;
    return (ushort)u;
}
static __device__ __forceinline__ float bf2f(ushort s) {
    return __builtin_bit_cast(float, (unsigned)s << 16);
}
// fast tanh via exp2
static __device__ __forceinline__ float tanh_fast(float x) {
    float ax = __builtin_fabsf(x);
    float e = __builtin_amdgcn_exp2f(ax * -2.885390081777927f);   // e^{-2ax}
    float t = (1.f - e) * __builtin_amdgcn_rcpf(1.f + e);
    return __builtin_copysignf(t, x);
}

// ---------------- fused prep kernel (all weight repacks / converts in ONE dispatch) ----
#define PB_POSES 19584
#define PB_K1A   21248
#define PB_K1B   22912
#define PB_K2A   28032
#define PB_K2B   33152
#define PB_WT1   33408
#define PB_WTB   37504
#define PB_WT7   37640
#define PB_A1    37742
#define PB_AB    38147
#define PB_A7    38249
#define PB_BN    39609
#define PB_Z     39610
#define PB_DCT   39615

__global__ __launch_bounds__(256) void prep_all(
    const float* __restrict__ poses, ushort* __restrict__ pb16,
    const float* __restrict__ kw1, const float* __restrict__ qw1,
    ushort* __restrict__ Wt1k, ushort* __restrict__ Wt1q,
    const float* __restrict__ kw2, const float* __restrict__ qw2,
    ushort* __restrict__ Wt2k, ushort* __restrict__ Wt2q,
    const float* __restrict__ gc1_w, ushort* __restrict__ WT1,
    const float* __restrict__ gcb_w, ushort* __restrict__ WTb,
    const float* __restrict__ gc7_w, ushort* __restrict__ WT7,
    const float* __restrict__ gc1_att, ushort* __restrict__ A16_1,
    const float* __restrict__ gcb_att, ushort* __restrict__ A16_B,
    const float* __restrict__ gc7_att, ushort* __restrict__ A16_7,
    const float* __restrict__ bn1_g, const float* __restrict__ bn1_b,
    const float* __restrict__ gcb_g, const float* __restrict__ gcb_beta,
    float* __restrict__ bnT, float* __restrict__ zpadf, float* __restrict__ dct)
{
    const int blk = blockIdx.x;
    const int tid = threadIdx.x;
    if (blk < PB_POSES) {
        int idx = blk * 256 + tid;
        int i = idx % NODEP;
        int row = (idx / NODEP) % POSE_ROWS;
        int b = idx / (NODEP * POSE_ROWS);
        float v = (i < NF) ? poses[((long long)b * POSE_ROWS + row) * NF + i] * 1e-3f : 0.f;
        pb16[idx] = f2bf(v);
    } else if (blk < PB_K1B) {
        int wi = blk - PB_POSES;
        const float* src = (wi < 1664) ? kw1 : qw1;
        ushort* dst = (wi < 1664) ? Wt1k : Wt1q;
        int idx = (wi % 1664) * 256 + tid;
        int n = idx / 832, k = idx % 832;
        int h = k / 136, i = k % 136;
        float v = (i < 135 && h < 6) ? src[((long long)n * 135 + i) * 6 + h] : 0.f;
        dst[idx] = f2bf(v);
    } else if (blk < PB_K2B) {
        int wi = blk - PB_K1B;
        const float* src = (wi < 5120) ? kw2 : qw2;
        ushort* dst = (wi < 5120) ? Wt2k : Wt2q;
        int idx = (wi % 5120) * 256 + tid;
        int n = idx / 2560, k = idx % 2560;
        int h = k / 512, i = k % 512;
        dst[idx] = f2bf(src[((long long)n * 512 + i) * 5 + h]);
    } else if (blk < PB_WT1) {
        int idx = (blk - PB_K2B) * 256 + tid;
        int n = idx / 128, k = idx % 128;
        WT1[idx] = f2bf((k < 68) ? gc1_w[(long long)k * 512 + n] : 0.f);
    } else if (blk < PB_WTB) {
        int g = (blk - PB_WT1) * 256 + tid;
        int L = g >> 18, idx = g & 262143;
        int n = idx / 512, k = idx % 512;
        WTb[g] = f2bf(gcb_w[(long long)L * 262144 + (long long)k * 512 + n]);
    } else if (blk < PB_WT7) {
        int idx = (blk - PB_WTB) * 256 + tid;
        int n = idx / 512, k = idx % 512;
        WT7[idx] = f2bf(gc7_w[(long long)k * 68 + n]);
    } else if (blk < PB_A1) {
        int idx = (blk - PB_WT7) * 256 + tid;
        if (idx < 135 * 192) {
            int r = idx / 192, c = idx % 192;
            A16_1[idx] = f2bf(c < 135 ? gc1_att[r * 135 + c] : 0.f);
        }
    } else if (blk < PB_AB) {
        int idx = (blk - PB_A1) * 256 + tid;
        int r = idx / 192, c = idx % 192;
        A16_B[idx] = f2bf(c < 135 ? gcb_att[r * 135 + c] : 0.f);
    } else if (blk < PB_A7) {
        int idx = (blk - PB_AB) * 256 + tid;
        if (idx < 135 * 192) {
            int r = idx / 192, c = idx % 192;
            A16_7[idx] = f2bf(c < 135 ? gc7_att[r * 135 + c] : 0.f);
        }
    } else if (blk < PB_BN) {
        int g = (blk - PB_A7) * 256 + tid;
        int p = g / 69632, idx = g % 69632;
        int node = idx % 136, m = idx / 136;
        const float* gs = (p == 0) ? bn1_g : (gcb_g + (p - 1) * 69120);
        const float* bs = (p == 0) ? bn1_b : (gcb_beta + (p - 1) * 69120);
        float* gt = bnT + (long long)p * 139264;
        float* bt = gt + 69632;
        gt[idx] = (node < 135) ? gs[node * 512 + m] : 0.f;
        bt[idx] = (node < 135) ? bs[node * 512 + m] : 0.f;
    } else if (blk < PB_Z) {
        if (tid < 128) zpadf[tid] = 0.f;
    } else {
        int idx = (blk - PB_Z) * 256 + tid;
        if (idx < DCTN * DCTN) {
            int k = idx / DCTN, i = idx % DCTN;
            double w = (k == 0) ? sqrt(1.0 / DCTN) : sqrt(2.0 / DCTN);
            dct[idx] = (float)(w * cos(3.14159265358979323846 * (i + 0.5) * k / (double)DCTN));
        }
    }
}

// ---------------- register-direct NT MFMA GEMM (no LDS, no barriers) ----------------
// C[m,n] = epi( sum_k A[m,k] * Bt[n,k] ).  K must be a multiple of 64; the
// zero-padded (weight-side) operand annihilates garbage in the K-pad region.
// A row off = (m/rpbA)*sAw + (m%rpbA)*sAr + bz*sAbz ; Bt row off = n*sBr + bz*sBbz
// C addr = bz*sCbz + m*sCm + n*sCn (same map for C16/resid).
// m0 = blockIdx.x*BM, n0 = blockIdx.y*BN. OOB rows clamp (results discarded).
template<int BM, int BN>
__global__ __launch_bounds__(256) void gemm3(
    const ushort* __restrict__ A, const ushort* __restrict__ Bt,
    int M, int N, int K,
    int rpbA, long long sAw, long long sAr, long long sAbz,
    long long sBr, long long sBbz,
    float* __restrict__ C, ushort* __restrict__ C16,
    long long sCbz, long long sCm, long long sCn,
    int do_relu, const float* __restrict__ bias, int bias_mode,
    const float* __restrict__ bnTg, const float* __restrict__ bnTb,
    int do_tanh, const ushort* __restrict__ resid16, const float* __restrict__ resid32)
{
    constexpr int SM = BM / 32, SN = BN / 32;
    const int tid = threadIdx.x;
    const int lane = tid & 63, w = tid >> 6;
    const int bz = blockIdx.z;
    const int m0 = blockIdx.x * BM, n0 = blockIdx.y * BN;
    const int wm = (w >> 1) * (BM / 2), wn = (w & 1) * (BN / 2);
    const int lc = lane & 15;
    const int kq = (lane >> 4) * 8;          // k sub-offset within a 32-k step

    const ushort* pA[SM];
    #pragma unroll
    for (int sm = 0; sm < SM; sm++) {
        int m = m0 + wm + sm * 16 + lc;
        if (m >= M) m = M - 1;
        pA[sm] = A + (long long)(m / rpbA) * sAw + (long long)(m % rpbA) * sAr
               + (long long)bz * sAbz + kq;
    }
    const ushort* pB[SN];
    #pragma unroll
    for (int sn = 0; sn < SN; sn++) {
        int n = n0 + wn + sn * 16 + lc;
        if (n >= N) n = N - 1;
        pB[sn] = Bt + (long long)n * sBr + (long long)bz * sBbz + kq;
    }

    floatx4 acc[SM][SN];
    #pragma unroll
    for (int i = 0; i < SM; i++)
        #pragma unroll
        for (int j = 0; j < SN; j++)
            acc[i][j] = (floatx4){0.f, 0.f, 0.f, 0.f};

    short8 a0[SM], b0[SN], a1[SM], b1[SN];

    #define LOADF(AR, BR) do {                                           \
        _Pragma("unroll")                                                \
        for (int sm = 0; sm < SM; sm++) { AR[sm] = *(const short8*)pA[sm]; pA[sm] += 32; } \
        _Pragma("unroll")                                                \
        for (int sn = 0; sn < SN; sn++) { BR[sn] = *(const short8*)pB[sn]; pB[sn] += 32; } \
    } while (0)
    #define DOMFMA(AR, BR) do {                                          \
        _Pragma("unroll")                                                \
        for (int sm = 0; sm < SM; sm++)                                  \
            _Pragma("unroll")                                            \
            for (int sn = 0; sn < SN; sn++)                              \
                acc[sm][sn] = __builtin_amdgcn_mfma_f32_16x16x32_bf16(AR[sm], BR[sn], acc[sm][sn], 0, 0, 0); \
    } while (0)

    LOADF(a0, b0);
    const int NIT = K >> 6;                  // K % 64 == 0 guaranteed
    for (int i = 0; i < NIT; i++) {
        LOADF(a1, b1);                       // prefetch k+32 while computing k
        DOMFMA(a0, b0);
        if (i + 1 < NIT) LOADF(a0, b0);      // prefetch k+64 while computing k+32
        DOMFMA(a1, b1);
    }
    #undef LOADF
    #undef DOMFMA

    // epilogue: D mapping col(n)=lane&15, row(m)=(lane>>4)*4+r
    const int lr4 = (lane >> 4) << 2;
    #pragma unroll
    for (int sm = 0; sm < SM; sm++) {
        #pragma unroll
        for (int sn = 0; sn < SN; sn++) {
            int n = n0 + wn + sn * 16 + lc;
            if (n >= N) continue;
            int node = n % 136;
            int mb = m0 + wm + sm * 16 + lr4;
            float vv[4];
            #pragma unroll
            for (int r = 0; r < 4; r++) {
                int m = mb + r;
                float v = acc[sm][sn][r];
                if (do_relu) v = fmaxf(v, 0.f);
                if (bias) v += (bias_mode == 1) ? bias[m < M ? m : 0] : bias[n];
                if (bnTg) {
                    long long gi = (long long)(m < M ? m : 0) * 136 + node;
                    v = bnTg[gi] * (v * BN_SCALE) + bnTb[gi];
                }
                if (do_tanh) v = tanh_fast(v);
                long long addr = (long long)bz * sCbz + (long long)m * sCm + (long long)n * sCn;
                if (m < M) {
                    if (resid16) v += bf2f(resid16[addr]);
                    else if (resid32) v += resid32[addr];
                    if (C) C[addr] = v;
                    if (C16 && sCm != 1) C16[addr] = f2bf(v);
                }
                vv[r] = v;
            }
            if (C16 && sCm == 1 && mb + 3 < M) {
                ushort4 pk;
                pk.x = f2bf(vv[0]); pk.y = f2bf(vv[1]); pk.z = f2bf(vv[2]); pk.w = f2bf(vv[3]);
                *(ushort4*)&C16[(long long)bz * sCbz + mb + (long long)n * sCn] = pk;
            }
        }
    }
}

// ---------------- attention scores + normalize (wave-parallel) ----------------
__global__ __launch_bounds__(256) void att_k(const float* __restrict__ kf, const float* __restrict__ qf,
                                             float* __restrict__ att) {
    int b = blockIdx.x;
    int tid = threadIdx.x;
    int lane = tid & 63, w = tid >> 6;
    __shared__ float s[96];
    __shared__ float ssum;
    const float* qb = qf + b * DD + lane * 8;
    float4 q0 = *(const float4*)qb;
    float4 q1 = *(const float4*)(qb + 4);
    const float* kb = kf + (long long)b * VN * DD;
    for (int v = w; v < VN; v += 4) {
        const float* kr = kb + v * DD + lane * 8;
        float4 k0 = *(const float4*)kr;
        float4 k1 = *(const float4*)(kr + 4);
        float p = q0.x * k0.x + q0.y * k0.y + q0.z * k0.z + q0.w * k0.w
                + q1.x * k1.x + q1.y * k1.y + q1.z * k1.z + q1.w * k1.w;
        #pragma unroll
        for (int off = 32; off; off >>= 1) p += __shfl_xor(p, off);
        if (lane == 0) s[v] = p + 1e-15f;
    }
    __syncthreads();
    if (tid < 64) {
        float p2 = (tid < VN ? s[tid] : 0.f) + ((tid + 64) < VN ? s[tid + 64] : 0.f);
        #pragma unroll
        for (int off = 32; off; off >>= 1) p2 += __shfl_xor(p2, off);
        if (tid == 0) ssum = p2;
    }
    __syncthreads();
    float inv = 1.f / ssum;
    for (int v = tid; v < VN; v += 256) att[b * VN + v] = s[v] * inv;
}

// ---------------- w34[b,t,f] = sum_v att[b,v] * poses[b,v+t,f] ----------------
__global__ void weighted_k(const float* __restrict__ poses, const float* __restrict__ att,
                           float* __restrict__ w34) {
    int t = blockIdx.x;
    int b = blockIdx.y;
    int f = threadIdx.x;
    if (f >= NF) return;
    const float* pb = poses + (long long)b * POSE_ROWS * NF + t * NF + f;
    const float* ab = att + b * VN;
    float acc = 0.f;
    for (int v = 0; v < VN; v++) acc += ab[v] * pb[v * NF];
    w34[(long long)b * DCTN * NF + t * NF + f] = acc;
}

// ---------------- x = concat(dct_in, dct_att); node-major f32 + feature-major bf16 ----
__global__ void build_x(const float* __restrict__ poses, const float* __restrict__ w34,
                        const float* __restrict__ dctm, float* __restrict__ x32,
                        ushort* __restrict__ xT16) {
    int idx = blockIdx.x * 256 + threadIdx.x;
    if (idx >= BATCH * NF * 68) return;
    int kk = idx % 68;
    int f = (idx / 68) % NF;
    int b = idx / (68 * NF);
    float acc = 0.f;
    if (kk < DCTN) {
        const float* pb = poses + (long long)b * POSE_ROWS * NF;
        #pragma unroll
        for (int t = 0; t < DCTN; t++) {
            int row = (t < KQ) ? (INN - KQ + t) : (INN - 1);
            acc += dctm[kk * DCTN + t] * pb[row * NF + f];
        }
    } else {
        int k2 = kk - DCTN;
        const float* wb = w34 + (long long)b * DCTN * NF + f;
        #pragma unroll
        for (int t = 0; t < DCTN; t++) acc += dctm[k2 * DCTN + t] * wb[t * NF];
    }
    long long R = (long long)b * NODEP + f;
    x32[R * 68 + kk] = acc;
    xT16[(long long)kk * RP + R] = f2bf(acc);
}

// ---------------- preds[b,t,f] = sum_k dct[k][10+t] * h32[(b*136+f)*68+k] ----------------
__global__ void idct_out(const float* __restrict__ h32, const float* __restrict__ dctm,
                         float* __restrict__ out) {
    int idx = blockIdx.x * 256 + threadIdx.x;
    if (idx >= BATCH * OUTN * NF) return;
    int f = idx % NF;
    int t = (idx / NF) % OUTN;
    int b = idx / (NF * OUTN);
    const float* yr = h32 + ((long long)b * NODEP + f) * 68;
    float acc = 0.f;
    #pragma unroll
    for (int k = 0; k < DCTN; k++) acc += dctm[k * DCTN + (KQ + t)] * yr[k];
    out[idx] = acc;
}

// ---------------- host ----------------
extern "C" void kernel_launch(void* const* d_in, const int* in_sizes, int n_in,
                              void* d_out, int out_size, void* d_ws, size_t ws_size,
                              hipStream_t stream) {
    const float* poses   = (const float*)d_in[0];
    const float* qw1     = (const float*)d_in[1];
    const float* qw2     = (const float*)d_in[2];
    const float* kw1     = (const float*)d_in[3];
    const float* kw2     = (const float*)d_in[4];
    const float* gc1_att = (const float*)d_in[5];
    const float* gc1_w   = (const float*)d_in[6];
    const float* gc1_b   = (const float*)d_in[7];
    const float* bn1_g   = (const float*)d_in[8];
    const float* bn1_b   = (const float*)d_in[9];
    const float* gcb_att = (const float*)d_in[10];
    const float* gcb_w   = (const float*)d_in[11];
    const float* gcb_b   = (const float*)d_in[12];
    const float* gcb_g   = (const float*)d_in[13];
    const float* gcb_beta= (const float*)d_in[14];
    const float* gc7_att = (const float*)d_in[15];
    const float* gc7_w   = (const float*)d_in[16];
    const float* gc7_b   = (const float*)d_in[17];
    float* out = (float*)d_out;
    float* w = (float*)d_ws;

    // ---- workspace layout (f32 units) ----
    float* dct   = w;                      // 1156 -> pad 1280
    float* att   = w + 1280;               // -> 23808
    float* w34   = w + 23808;              // -> 1198848
    float* x32   = w + 1198848;            // RP*68 -> 3566336
    float* h32   = w + 3566336;            // RP*68 -> 5933824
    float* qf    = w + 5933824;            // -> 6064896
    ushort* su   = (ushort*)(w + 6064896); // bf16 weight region
    ushort* WT1    = su;                   // 512*128   = 65536
    ushort* WTb    = su + 65536;           // 4*512*512 = 1048576
    ushort* WT7    = su + 1114112;         // 68*512    = 34816
    ushort* A16_1  = su + 1148928;         // 135*192   = 25920
    ushort* A16_B  = su + 1174848;         // 540*192   = 103680
    ushort* A16_7  = su + 1278528;         // 25920
    float* bnT   = w + 6717120;            // 10 * 69632 -> 7413440
    float* kf    = w + 7413440;            // 256*87*512 -> 18816704
    ushort* R2   = (ushort*)(w + 18816704);
    ushort* yT16  = R2;
    ushort* r1k16 = R2;                    // phase-A alias
    ushort* r1q16 = R2 + 11927552;
    ushort* R3   = (ushort*)(w + 27729600);
    ushort* hT16  = R3;
    ushort* pb16  = R3;                    // phase-A alias
    ushort* Wt1k  = R3 + 5013504;
    ushort* Wt1q  = R3 + 5439488;
    ushort* Wt2k  = R3 + 5865472;
    ushort* Wt2q  = R3 + 7176192;
    ushort* R4   = (ushort*)(w + 36642496);
    ushort* zN16  = R4;
    ushort* xT16  = R4;                    // alias (dead before zN16 written)
    ushort* z116  = R4 + 2367488;          // RP*80
    float* zpadf = w + 45555392;           // 128 f zero page
    (void)zpadf;

    const int INF_RPB = 1 << 30;

    // ---- fused prep (one dispatch) ----
    prep_all<<<PB_DCT, 256, 0, stream>>>(
        poses, pb16, kw1, qw1, Wt1k, Wt1q, kw2, qw2, Wt2k, Wt2q,
        gc1_w, WT1, gcb_w, WTb, gc7_w, WT7,
        gc1_att, A16_1, gcb_att, A16_B, gc7_att, A16_7,
        bn1_g, bn1_b, gcb_g, gcb_beta, bnT, zpadf, dct);

    // ---- conv stack (grid: x = m-blocks, y = n-blocks) ----
    gemm3<128,128><<<dim3(182, 4, 1), 256, 0, stream>>>(pb16, Wt1k, 23296, 512, 832,
        91, 19584LL, 136LL, 0LL, 832LL, 0LL,
        (float*)nullptr, r1k16, 0LL, 512LL, 1LL, 1, nullptr, 0, nullptr, nullptr, 0, nullptr, nullptr);
    gemm3<128,128><<<dim3(10, 4, 1), 256, 0, stream>>>(pb16 + 110*136, Wt1q, 1280, 512, 832,
        5, 19584LL, 136LL, 0LL, 832LL, 0LL,
        (float*)nullptr, r1q16, 0LL, 512LL, 1LL, 1, nullptr, 0, nullptr, nullptr, 0, nullptr, nullptr);
    gemm3<128,128><<<dim3(174, 4, 1), 256, 0, stream>>>(r1k16, Wt2k, 22272, 512, 2560,
        87, 46592LL, 512LL, 0LL, 2560LL, 0LL,
        kf, (ushort*)nullptr, 0LL, 512LL, 1LL, 1, nullptr, 0, nullptr, nullptr, 0, nullptr, nullptr);
    gemm3<64,64><<<dim3(4, 8, 1), 256, 0, stream>>>(r1q16, Wt2q, 256, 512, 2560,
        INF_RPB, 0LL, 2560LL, 0LL, 2560LL, 0LL,
        qf, (ushort*)nullptr, 0LL, 512LL, 1LL, 1, nullptr, 0, nullptr, nullptr, 0, nullptr, nullptr);

    // ---- attention + x ----
    att_k<<<BATCH, 256, 0, stream>>>(kf, qf, att);
    weighted_k<<<dim3(DCTN, BATCH), 192, 0, stream>>>(poses, att, w34);
    build_x<<<(BATCH * NF * 68 + 255) / 256, 256, 0, stream>>>(poses, w34, dct, x32, xT16);

    // ---- gc1: mix then W(68->512) ----
    gemm3<64,64><<<dim3(2, 3, BATCH), 256, 0, stream>>>(xT16, A16_1, 68, 135, 192,
        INF_RPB, 0LL, (long long)RP, 136LL, 192LL, 0LL,
        (float*)nullptr, z116, 10880LL, 1LL, 80LL, 0, nullptr, 0, nullptr, nullptr, 0, nullptr, nullptr);
    gemm3<128,128><<<dim3(4, 272, 1), 256, 0, stream>>>(WT1, z116, 512, RP, 128,
        INF_RPB, 0LL, 128LL, 0LL, 80LL, 0LL,
        (float*)nullptr, yT16, 0LL, (long long)RP, 1LL, 0, gc1_b, 1, bnT, bnT + 69632, 1, nullptr, nullptr);

    // ---- residual GCN blocks ----
    for (int L = 0; L < 4; L++) {
        const ushort* min = (L & 1) ? hT16 : yT16;
        gemm3<64,64><<<dim3(8, 3, BATCH), 256, 0, stream>>>(min, A16_B + L*25920, 512, 135, 192,
            INF_RPB, 0LL, (long long)RP, 136LL, 192LL, 0LL,
            (float*)nullptr, zN16, 69632LL, 1LL, 512LL, 0, nullptr, 0, nullptr, nullptr, 0, nullptr, nullptr);
        gemm3<128,128><<<dim3(4, 272, 1), 256, 0, stream>>>(WTb + L*262144, zN16, 512, RP, 512,
            INF_RPB, 0LL, 512LL, 0LL, 512LL, 0LL,
            (float*)nullptr, (L & 1) ? yT16 : hT16, 0LL, (long long)RP, 1LL,
            0, gcb_b + L*512, 1, bnT + (1 + L) * 139264, bnT + (1 + L) * 139264 + 69632, 1,
            (L & 1) ? yT16 : (const ushort*)nullptr, nullptr);
    }

    // ---- gc7: mix then W(512->68) + bias + x residual ----
    gemm3<64,64><<<dim3(8, 3, BATCH), 256, 0, stream>>>(yT16, A16_7, 512, 135, 192,
        INF_RPB, 0LL, (long long)RP, 136LL, 192LL, 0LL,
        (float*)nullptr, zN16, 69632LL, 1LL, 512LL, 0, nullptr, 0, nullptr, nullptr, 0, nullptr, nullptr);
    gemm3<64,64><<<dim3(544, 2, 1), 256, 0, stream>>>(zN16, WT7, RP, 68, 512,
        INF_RPB, 0LL, 512LL, 0LL, 512LL, 0LL,
        h32, (ushort*)nullptr, 0LL, 68LL, 1LL, 0, gc7_b, 2, nullptr, nullptr, 0, nullptr, x32);

    idct_out<<<(BATCH * OUTN * NF + 255) / 256, 256, 0, stream>>>(h32, dct, out);
}

// Round 7
// 1730.401 us; speedup vs baseline: 1.0257x; 1.0257x over previous
//
#include <hip/hip_runtime.h>
#include <math.h>

// ---------------- problem constants ----------------
#define POSE_ROWS 144
#define NF 135
#define DD 512
#define KQ 10
#define DCTN 34
#define INN 120
#define OUTN 24
#define VN 87
#define BATCH 256
#define RP 34816              // padded row dim: 256 * 136
#define NODEP 136
#define BN_SCALE 0.9999950000374997f

typedef __attribute__((ext_vector_type(8))) short short8;
typedef __attribute__((ext_vector_type(4))) float floatx4;

static __device__ __forceinline__ ushort f2bf(float f) {
    unsigned u = __builtin_bit_cast(unsigned, f);
    u = (u + 0x7FFFu + ((u >> 16) & 1u)) >> 16;
    return (ushort)u;
}
static __device__ __forceinline__ float bf2f(ushort s) {
    return __builtin_bit_cast(float, (unsigned)s << 16);
}
// fast tanh via exp2
static __device__ __forceinline__ float tanh_fast(float x) {
    float ax = __builtin_fabsf(x);
    float e = __builtin_amdgcn_exp2f(ax * -2.885390081777927f);   // e^{-2ax}
    float t = (1.f - e) * __builtin_amdgcn_rcpf(1.f + e);
    return __builtin_copysignf(t, x);
}

// ---------------- fused prep kernel (all weight repacks / converts in ONE dispatch) ----
#define PB_POSES 19584
#define PB_K1A   21248
#define PB_K1B   22912
#define PB_K2A   28032
#define PB_K2B   33152
#define PB_WT1   33408
#define PB_WTB   37504
#define PB_WT7   37640
#define PB_A1    37742
#define PB_AB    38147
#define PB_A7    38249
#define PB_BN    39609
#define PB_Z     39610
#define PB_DCT   39615

__global__ __launch_bounds__(256) void prep_all(
    const float* __restrict__ poses, ushort* __restrict__ pb16,
    const float* __restrict__ kw1, const float* __restrict__ qw1,
    ushort* __restrict__ Wt1k, ushort* __restrict__ Wt1q,
    const float* __restrict__ kw2, const float* __restrict__ qw2,
    ushort* __restrict__ Wt2k, ushort* __restrict__ Wt2q,
    const float* __restrict__ gc1_w, ushort* __restrict__ WT1,
    const float* __restrict__ gcb_w, ushort* __restrict__ WTb,
    const float* __restrict__ gc7_w, ushort* __restrict__ WT7,
    const float* __restrict__ gc1_att, ushort* __restrict__ A16_1,
    const float* __restrict__ gcb_att, ushort* __restrict__ A16_B,
    const float* __restrict__ gc7_att, ushort* __restrict__ A16_7,
    const float* __restrict__ bn1_g, const float* __restrict__ bn1_b,
    const float* __restrict__ gcb_g, const float* __restrict__ gcb_beta,
    float* __restrict__ bnT, float* __restrict__ zpadf, float* __restrict__ dct)
{
    const int blk = blockIdx.x;
    const int tid = threadIdx.x;
    if (blk < PB_POSES) {
        int idx = blk * 256 + tid;
        int i = idx % NODEP;
        int row = (idx / NODEP) % POSE_ROWS;
        int b = idx / (NODEP * POSE_ROWS);
        float v = (i < NF) ? poses[((long long)b * POSE_ROWS + row) * NF + i] * 1e-3f : 0.f;
        pb16[idx] = f2bf(v);
    } else if (blk < PB_K1B) {
        int wi = blk - PB_POSES;
        const float* src = (wi < 1664) ? kw1 : qw1;
        ushort* dst = (wi < 1664) ? Wt1k : Wt1q;
        int idx = (wi % 1664) * 256 + tid;
        int n = idx / 832, k = idx % 832;
        int h = k / 136, i = k % 136;
        float v = (i < 135 && h < 6) ? src[((long long)n * 135 + i) * 6 + h] : 0.f;
        dst[idx] = f2bf(v);
    } else if (blk < PB_K2B) {
        int wi = blk - PB_K1B;
        const float* src = (wi < 5120) ? kw2 : qw2;
        ushort* dst = (wi < 5120) ? Wt2k : Wt2q;
        int idx = (wi % 5120) * 256 + tid;
        int n = idx / 2560, k = idx % 2560;
        int h = k / 512, i = k % 512;
        dst[idx] = f2bf(src[((long long)n * 512 + i) * 5 + h]);
    } else if (blk < PB_WT1) {
        int idx = (blk - PB_K2B) * 256 + tid;
        int n = idx / 128, k = idx % 128;
        WT1[idx] = f2bf((k < 68) ? gc1_w[(long long)k * 512 + n] : 0.f);
    } else if (blk < PB_WTB) {
        int g = (blk - PB_WT1) * 256 + tid;
        int L = g >> 18, idx = g & 262143;
        int n = idx / 512, k = idx % 512;
        WTb[g] = f2bf(gcb_w[(long long)L * 262144 + (long long)k * 512 + n]);
    } else if (blk < PB_WT7) {
        int idx = (blk - PB_WTB) * 256 + tid;
        int n = idx / 512, k = idx % 512;
        WT7[idx] = f2bf(gc7_w[(long long)k * 68 + n]);
    } else if (blk < PB_A1) {
        int idx = (blk - PB_WT7) * 256 + tid;
        if (idx < 135 * 192) {
            int r = idx / 192, c = idx % 192;
            A16_1[idx] = f2bf(c < 135 ? gc1_att[r * 135 + c] : 0.f);
        }
    } else if (blk < PB_AB) {
        int idx = (blk - PB_A1) * 256 + tid;
        int r = idx / 192, c = idx % 192;
        A16_B[idx] = f2bf(c < 135 ? gcb_att[r * 135 + c] : 0.f);
    } else if (blk < PB_A7) {
        int idx = (blk - PB_AB) * 256 + tid;
        if (idx < 135 * 192) {
            int r = idx / 192, c = idx % 192;
            A16_7[idx] = f2bf(c < 135 ? gc7_att[r * 135 + c] : 0.f);
        }
    } else if (blk < PB_BN) {
        int g = (blk - PB_A7) * 256 + tid;
        int p = g / 69632, idx = g % 69632;
        int node = idx % 136, m = idx / 136;
        const float* gs = (p == 0) ? bn1_g : (gcb_g + (p - 1) * 69120);
        const float* bs = (p == 0) ? bn1_b : (gcb_beta + (p - 1) * 69120);
        float* gt = bnT + (long long)p * 139264;
        float* bt = gt + 69632;
        gt[idx] = (node < 135) ? gs[node * 512 + m] : 0.f;
        bt[idx] = (node < 135) ? bs[node * 512 + m] : 0.f;
    } else if (blk < PB_Z) {
        if (tid < 128) zpadf[tid] = 0.f;
    } else {
        int idx = (blk - PB_Z) * 256 + tid;
        if (idx < DCTN * DCTN) {
            int k = idx / DCTN, i = idx % DCTN;
            double w = (k == 0) ? sqrt(1.0 / DCTN) : sqrt(2.0 / DCTN);
            dct[idx] = (float)(w * cos(3.14159265358979323846 * (i + 0.5) * k / (double)DCTN));
        }
    }
}

// ---------------- register-direct NT MFMA GEMM: 1 wave/block, 64x64 tile ------------
// No LDS, no barriers. XCD-aware block swizzle:
//   mode 0: linear            mb = gx % MBc ; nb = gx / MBc
//   mode 1: n-partitioned     (B-stream confined per XCD, m-blocks inner/reused in L2)
//   mode 2: m-partitioned     (A-stream confined per XCD, n-blocks inner/reused in L2)
// C[m,n] = epi( sum_k A[m,k] * Bt[n,k] ); K % 64 == 0; zero-padded weight operand
// annihilates K-pad garbage. OOB tiles early-return (safe: no barriers).
__global__ __launch_bounds__(64) void gemm4(
    const ushort* __restrict__ A, const ushort* __restrict__ Bt,
    int M, int N, int K,
    int mode, int MBc, int NBc, int Pc,
    int rpbA, long long sAw, long long sAr, long long sAbz,
    long long sBr, long long sBbz,
    float* __restrict__ C, ushort* __restrict__ C16,
    long long sCbz, long long sCm, long long sCn,
    int do_relu, const float* __restrict__ bias, int bias_mode,
    const float* __restrict__ bnTg, const float* __restrict__ bnTb,
    int do_tanh, const ushort* __restrict__ resid16, const float* __restrict__ resid32)
{
    int gx = blockIdx.x;
    int mb, nb;
    if (mode == 0)      { mb = gx % MBc; nb = gx / MBc; }
    else if (mode == 1) { int x = gx & 7, s = gx >> 3; mb = s % MBc; nb = x * Pc + s / MBc; }
    else                { int x = gx & 7, s = gx >> 3; nb = s % NBc; mb = x * Pc + s / NBc; }
    const int m0 = mb * 64, n0 = nb * 64;
    if (m0 >= M || n0 >= N) return;

    const int bz = blockIdx.z;
    const int lane = threadIdx.x;            // 0..63 (one wave)
    const int lc = lane & 15;
    const int kq = (lane >> 4) * 8;          // k sub-offset within a 32-k step

    const ushort* pA[4];
    #pragma unroll
    for (int sm = 0; sm < 4; sm++) {
        int m = m0 + sm * 16 + lc;
        if (m >= M) m = M - 1;
        pA[sm] = A + (long long)(m / rpbA) * sAw + (long long)(m % rpbA) * sAr
               + (long long)bz * sAbz + kq;
    }
    const ushort* pB[4];
    #pragma unroll
    for (int sn = 0; sn < 4; sn++) {
        int n = n0 + sn * 16 + lc;
        if (n >= N) n = N - 1;
        pB[sn] = Bt + (long long)n * sBr + (long long)bz * sBbz + kq;
    }

    floatx4 acc[4][4];
    #pragma unroll
    for (int i = 0; i < 4; i++)
        #pragma unroll
        for (int j = 0; j < 4; j++)
            acc[i][j] = (floatx4){0.f, 0.f, 0.f, 0.f};

    short8 a0[4], b0[4], a1[4], b1[4];

    #define LOADF(AR, BR) do {                                           \
        _Pragma("unroll")                                                \
        for (int sm = 0; sm < 4; sm++) { AR[sm] = *(const short8*)pA[sm]; pA[sm] += 32; } \
        _Pragma("unroll")                                                \
        for (int sn = 0; sn < 4; sn++) { BR[sn] = *(const short8*)pB[sn]; pB[sn] += 32; } \
    } while (0)
    #define DOMFMA(AR, BR) do {                                          \
        _Pragma("unroll")                                                \
        for (int sm = 0; sm < 4; sm++)                                   \
            _Pragma("unroll")                                            \
            for (int sn = 0; sn < 4; sn++)                               \
                acc[sm][sn] = __builtin_amdgcn_mfma_f32_16x16x32_bf16(AR[sm], BR[sn], acc[sm][sn], 0, 0, 0); \
    } while (0)

    LOADF(a0, b0);
    const int NIT = K >> 6;                  // K % 64 == 0 guaranteed
    for (int i = 0; i < NIT; i++) {
        LOADF(a1, b1);                       // prefetch k+32 while computing k
        DOMFMA(a0, b0);
        if (i + 1 < NIT) LOADF(a0, b0);      // prefetch k+64 while computing k+32
        DOMFMA(a1, b1);
    }
    #undef LOADF
    #undef DOMFMA

    // epilogue: D mapping col(n)=lane&15, row(m)=(lane>>4)*4+r
    const int lr4 = (lane >> 4) << 2;
    #pragma unroll
    for (int sm = 0; sm < 4; sm++) {
        #pragma unroll
        for (int sn = 0; sn < 4; sn++) {
            int n = n0 + sn * 16 + lc;
            if (n >= N) continue;
            int node = n % 136;
            int mbase = m0 + sm * 16 + lr4;
            float vv[4];
            #pragma unroll
            for (int r = 0; r < 4; r++) {
                int m = mbase + r;
                float v = acc[sm][sn][r];
                if (do_relu) v = fmaxf(v, 0.f);
                if (bias) v += (bias_mode == 1) ? bias[m < M ? m : 0] : bias[n];
                if (bnTg) {
                    long long gi = (long long)(m < M ? m : 0) * 136 + node;
                    v = bnTg[gi] * (v * BN_SCALE) + bnTb[gi];
                }
                if (do_tanh) v = tanh_fast(v);
                long long addr = (long long)bz * sCbz + (long long)m * sCm + (long long)n * sCn;
                if (m < M) {
                    if (resid16) v += bf2f(resid16[addr]);
                    else if (resid32) v += resid32[addr];
                    if (C) C[addr] = v;
                    if (C16 && sCm != 1) C16[addr] = f2bf(v);
                }
                vv[r] = v;
            }
            if (C16 && sCm == 1 && mbase + 3 < M) {
                ushort4 pk;
                pk.x = f2bf(vv[0]); pk.y = f2bf(vv[1]); pk.z = f2bf(vv[2]); pk.w = f2bf(vv[3]);
                *(ushort4*)&C16[(long long)bz * sCbz + mbase + (long long)n * sCn] = pk;
            }
        }
    }
}

// ---------------- attention scores + normalize (wave-parallel) ----------------
__global__ __launch_bounds__(256) void att_k(const float* __restrict__ kf, const float* __restrict__ qf,
                                             float* __restrict__ att) {
    int b = blockIdx.x;
    int tid = threadIdx.x;
    int lane = tid & 63, w = tid >> 6;
    __shared__ float s[96];
    __shared__ float ssum;
    const float* qb = qf + b * DD + lane * 8;
    float4 q0 = *(const float4*)qb;
    float4 q1 = *(const float4*)(qb + 4);
    const float* kb = kf + (long long)b * VN * DD;
    for (int v = w; v < VN; v += 4) {
        const float* kr = kb + v * DD + lane * 8;
        float4 k0 = *(const float4*)kr;
        float4 k1 = *(const float4*)(kr + 4);
        float p = q0.x * k0.x + q0.y * k0.y + q0.z * k0.z + q0.w * k0.w
                + q1.x * k1.x + q1.y * k1.y + q1.z * k1.z + q1.w * k1.w;
        #pragma unroll
        for (int off = 32; off; off >>= 1) p += __shfl_xor(p, off);
        if (lane == 0) s[v] = p + 1e-15f;
    }
    __syncthreads();
    if (tid < 64) {
        float p2 = (tid < VN ? s[tid] : 0.f) + ((tid + 64) < VN ? s[tid + 64] : 0.f);
        #pragma unroll
        for (int off = 32; off; off >>= 1) p2 += __shfl_xor(p2, off);
        if (tid == 0) ssum = p2;
    }
    __syncthreads();
    float inv = 1.f / ssum;
    for (int v = tid; v < VN; v += 256) att[b * VN + v] = s[v] * inv;
}

// ---------------- w34[b,t,f] = sum_v att[b,v] * poses[b,v+t,f] ----------------
__global__ void weighted_k(const float* __restrict__ poses, const float* __restrict__ att,
                           float* __restrict__ w34) {
    int t = blockIdx.x;
    int b = blockIdx.y;
    int f = threadIdx.x;
    if (f >= NF) return;
    const float* pb = poses + (long long)b * POSE_ROWS * NF + t * NF + f;
    const float* ab = att + b * VN;
    float acc = 0.f;
    for (int v = 0; v < VN; v++) acc += ab[v] * pb[v * NF];
    w34[(long long)b * DCTN * NF + t * NF + f] = acc;
}

// ---------------- x = concat(dct_in, dct_att); node-major f32 + feature-major bf16 ----
__global__ void build_x(const float* __restrict__ poses, const float* __restrict__ w34,
                        const float* __restrict__ dctm, float* __restrict__ x32,
                        ushort* __restrict__ xT16) {
    int idx = blockIdx.x * 256 + threadIdx.x;
    if (idx >= BATCH * NF * 68) return;
    int kk = idx % 68;
    int f = (idx / 68) % NF;
    int b = idx / (68 * NF);
    float acc = 0.f;
    if (kk < DCTN) {
        const float* pb = poses + (long long)b * POSE_ROWS * NF;
        #pragma unroll
        for (int t = 0; t < DCTN; t++) {
            int row = (t < KQ) ? (INN - KQ + t) : (INN - 1);
            acc += dctm[kk * DCTN + t] * pb[row * NF + f];
        }
    } else {
        int k2 = kk - DCTN;
        const float* wb = w34 + (long long)b * DCTN * NF + f;
        #pragma unroll
        for (int t = 0; t < DCTN; t++) acc += dctm[k2 * DCTN + t] * wb[t * NF];
    }
    long long R = (long long)b * NODEP + f;
    x32[R * 68 + kk] = acc;
    xT16[(long long)kk * RP + R] = f2bf(acc);
}

// ---------------- preds[b,t,f] = sum_k dct[k][10+t] * h32[(b*136+f)*68+k] ----------------
__global__ void idct_out(const float* __restrict__ h32, const float* __restrict__ dctm,
                         float* __restrict__ out) {
    int idx = blockIdx.x * 256 + threadIdx.x;
    if (idx >= BATCH * OUTN * NF) return;
    int f = idx % NF;
    int t = (idx / NF) % OUTN;
    int b = idx / (NF * OUTN);
    const float* yr = h32 + ((long long)b * NODEP + f) * 68;
    float acc = 0.f;
    #pragma unroll
    for (int k = 0; k < DCTN; k++) acc += dctm[k * DCTN + (KQ + t)] * yr[k];
    out[idx] = acc;
}

// ---------------- host ----------------
extern "C" void kernel_launch(void* const* d_in, const int* in_sizes, int n_in,
                              void* d_out, int out_size, void* d_ws, size_t ws_size,
                              hipStream_t stream) {
    const float* poses   = (const float*)d_in[0];
    const float* qw1     = (const float*)d_in[1];
    const float* qw2     = (const float*)d_in[2];
    const float* kw1     = (const float*)d_in[3];
    const float* kw2     = (const float*)d_in[4];
    const float* gc1_att = (const float*)d_in[5];
    const float* gc1_w   = (const float*)d_in[6];
    const float* gc1_b   = (const float*)d_in[7];
    const float* bn1_g   = (const float*)d_in[8];
    const float* bn1_b   = (const float*)d_in[9];
    const float* gcb_att = (const float*)d_in[10];
    const float* gcb_w   = (const float*)d_in[11];
    const float* gcb_b   = (const float*)d_in[12];
    const float* gcb_g   = (const float*)d_in[13];
    const float* gcb_beta= (const float*)d_in[14];
    const float* gc7_att = (const float*)d_in[15];
    const float* gc7_w   = (const float*)d_in[16];
    const float* gc7_b   = (const float*)d_in[17];
    float* out = (float*)d_out;
    float* w = (float*)d_ws;

    // ---- workspace layout (f32 units) ----
    float* dct   = w;                      // 1156 -> pad 1280
    float* att   = w + 1280;               // -> 23808
    float* w34   = w + 23808;              // -> 1198848
    float* x32   = w + 1198848;            // RP*68 -> 3566336
    float* h32   = w + 3566336;            // RP*68 -> 5933824
    float* qf    = w + 5933824;            // -> 6064896
    ushort* su   = (ushort*)(w + 6064896); // bf16 weight region
    ushort* WT1    = su;                   // 512*128   = 65536
    ushort* WTb    = su + 65536;           // 4*512*512 = 1048576
    ushort* WT7    = su + 1114112;         // 68*512    = 34816
    ushort* A16_1  = su + 1148928;         // 135*192   = 25920
    ushort* A16_B  = su + 1174848;         // 540*192   = 103680
    ushort* A16_7  = su + 1278528;         // 25920
    float* bnT   = w + 6717120;            // 10 * 69632 -> 7413440
    float* kf    = w + 7413440;            // 256*87*512 -> 18816704
    ushort* R2   = (ushort*)(w + 18816704);
    ushort* yT16  = R2;
    ushort* r1k16 = R2;                    // phase-A alias
    ushort* r1q16 = R2 + 11927552;
    ushort* R3   = (ushort*)(w + 27729600);
    ushort* hT16  = R3;
    ushort* pb16  = R3;                    // phase-A alias
    ushort* Wt1k  = R3 + 5013504;
    ushort* Wt1q  = R3 + 5439488;
    ushort* Wt2k  = R3 + 5865472;
    ushort* Wt2q  = R3 + 7176192;
    ushort* R4   = (ushort*)(w + 36642496);
    ushort* zN16  = R4;
    ushort* xT16  = R4;                    // alias (dead before zN16 written)
    ushort* z116  = R4 + 2367488;          // RP*80
    float* zpadf = w + 45555392;           // 128 f zero page

    const int INF_RPB = 1 << 30;

    // ---- fused prep (one dispatch) ----
    prep_all<<<PB_DCT, 256, 0, stream>>>(
        poses, pb16, kw1, qw1, Wt1k, Wt1q, kw2, qw2, Wt2k, Wt2q,
        gc1_w, WT1, gcb_w, WTb, gc7_w, WT7,
        gc1_att, A16_1, gcb_att, A16_B, gc7_att, A16_7,
        bn1_g, bn1_b, gcb_g, gcb_beta, bnT, zpadf, dct);

    // ---- conv stack ----
    // conv1k: A-stream (poses windows) m-partitioned per XCD (mode 2)
    gemm4<<<dim3(2944, 1, 1), 64, 0, stream>>>(pb16, Wt1k, 23296, 512, 832,
        2, 364, 8, 46, 91, 19584LL, 136LL, 0LL, 832LL, 0LL,
        (float*)nullptr, r1k16, 0LL, 512LL, 1LL, 1, nullptr, 0, nullptr, nullptr, 0, nullptr, nullptr);
    gemm4<<<dim3(160, 1, 1), 64, 0, stream>>>(pb16 + 110*136, Wt1q, 1280, 512, 832,
        0, 20, 8, 0, 5, 19584LL, 136LL, 0LL, 832LL, 0LL,
        (float*)nullptr, r1q16, 0LL, 512LL, 1LL, 1, nullptr, 0, nullptr, nullptr, 0, nullptr, nullptr);
    gemm4<<<dim3(2816, 1, 1), 64, 0, stream>>>(r1k16, Wt2k, 22272, 512, 2560,
        2, 348, 8, 44, 87, 46592LL, 512LL, 0LL, 2560LL, 0LL,
        kf, (ushort*)nullptr, 0LL, 512LL, 1LL, 1, nullptr, 0, nullptr, nullptr, 0, nullptr, nullptr);
    gemm4<<<dim3(32, 1, 1), 64, 0, stream>>>(r1q16, Wt2q, 256, 512, 2560,
        0, 4, 8, 0, INF_RPB, 0LL, 2560LL, 0LL, 2560LL, 0LL,
        qf, (ushort*)nullptr, 0LL, 512LL, 1LL, 1, nullptr, 0, nullptr, nullptr, 0, nullptr, nullptr);

    // ---- attention + x ----
    att_k<<<BATCH, 256, 0, stream>>>(kf, qf, att);
    weighted_k<<<dim3(DCTN, BATCH), 192, 0, stream>>>(poses, att, w34);
    build_x<<<(BATCH * NF * 68 + 255) / 256, 256, 0, stream>>>(poses, w34, dct, x32, xT16);

    // ---- gc1: mix then W(68->512) ----
    gemm4<<<dim3(6, 1, BATCH), 64, 0, stream>>>(xT16, A16_1, 68, 135, 192,
        0, 2, 3, 0, INF_RPB, 0LL, (long long)RP, 136LL, 192LL, 0LL,
        (float*)nullptr, z116, 10880LL, 1LL, 80LL, 0, nullptr, 0, nullptr, nullptr, 0, nullptr, nullptr);
    // gc1 W: B-stream (z116, RP-wide) n-partitioned per XCD (mode 1)
    gemm4<<<dim3(4352, 1, 1), 64, 0, stream>>>(WT1, z116, 512, RP, 128,
        1, 8, 544, 68, INF_RPB, 0LL, 128LL, 0LL, 80LL, 0LL,
        (float*)nullptr, yT16, 0LL, (long long)RP, 1LL, 0, gc1_b, 1, bnT, bnT + 69632, 1, nullptr, nullptr);

    // ---- residual GCN blocks ----
    for (int L = 0; L < 4; L++) {
        const ushort* min = (L & 1) ? hT16 : yT16;
        gemm4<<<dim3(24, 1, BATCH), 64, 0, stream>>>(min, A16_B + L*25920, 512, 135, 192,
            0, 8, 3, 0, INF_RPB, 0LL, (long long)RP, 136LL, 192LL, 0LL,
            (float*)nullptr, zN16, 69632LL, 1LL, 512LL, 0, nullptr, 0, nullptr, nullptr, 0, nullptr, nullptr);
        gemm4<<<dim3(4352, 1, 1), 64, 0, stream>>>(WTb + L*262144, zN16, 512, RP, 512,
            1, 8, 544, 68, INF_RPB, 0LL, 512LL, 0LL, 512LL, 0LL,
            (float*)nullptr, (L & 1) ? yT16 : hT16, 0LL, (long long)RP, 1LL,
            0, gcb_b + L*512, 1, bnT + (1 + L) * 139264, bnT + (1 + L) * 139264 + 69632, 1,
            (L & 1) ? yT16 : (const ushort*)nullptr, nullptr);
    }

    // ---- gc7: mix then W(512->68) + bias + x residual ----
    gemm4<<<dim3(24, 1, BATCH), 64, 0, stream>>>(yT16, A16_7, 512, 135, 192,
        0, 8, 3, 0, INF_RPB, 0LL, (long long)RP, 136LL, 192LL, 0LL,
        (float*)nullptr, zN16, 69632LL, 1LL, 512LL, 0, nullptr, 0, nullptr, nullptr, 0, nullptr, nullptr);
    // gc7 W: A-stream (zN16, RP rows) m-partitioned per XCD (mode 2)
    gemm4<<<dim3(1088, 1, 1), 64, 0, stream>>>(zN16, WT7, RP, 68, 512,
        2, 544, 2, 68, INF_RPB, 0LL, 512LL, 0LL, 512LL, 0LL,
        h32, (ushort*)nullptr, 0LL, 68LL, 1LL, 0, gc7_b, 2, nullptr, nullptr, 0, nullptr, x32);

    idct_out<<<(BATCH * OUTN * NF + 255) / 256, 256, 0, stream>>>(h32, dct, out);
}

// Round 8
// 1271.369 us; speedup vs baseline: 1.3960x; 1.3611x over previous
//
#include <hip/hip_runtime.h>
#include <math.h>

// ---------------- problem constants ----------------
#define POSE_ROWS 144
#define NF 135
#define DD 512
#define KQ 10
#define DCTN 34
#define INN 120
#define OUTN 24
#define VN 87
#define BATCH 256
#define RP 34816              // padded row dim: 256 * 136
#define NODEP 136
#define BN_SCALE 0.9999950000374997f

typedef __attribute__((ext_vector_type(8))) short short8;
typedef __attribute__((ext_vector_type(4))) float floatx4;

static __device__ __forceinline__ ushort f2bf(float f) {
    unsigned u = __builtin_bit_cast(unsigned, f);
    u = (u + 0x7FFFu + ((u >> 16) & 1u)) >> 16;
    return (ushort)u;
}
static __device__ __forceinline__ float bf2f(ushort s) {
    return __builtin_bit_cast(float, (unsigned)s << 16);
}
static __device__ __forceinline__ float tanh_fast(float x) {
    float ax = __builtin_fabsf(x);
    float e = __builtin_amdgcn_exp2f(ax * -2.885390081777927f);   // e^{-2ax}
    float t = (1.f - e) * __builtin_amdgcn_rcpf(1.f + e);
    return __builtin_copysignf(t, x);
}

#define GLOAD_LDS(gp, lp) __builtin_amdgcn_global_load_lds( \
    (const __attribute__((address_space(1))) unsigned int*)(const void*)(gp), \
    (__attribute__((address_space(3))) unsigned int*)(void*)(lp), 16, 0, 0)

// ---------------- fused prep kernel ----------------
#define PB_POSES 19584
#define PB_K1B   22912
#define PB_K2B   33152
#define PB_WT1   33344
#define PB_WTB   37440
#define PB_WT7   37576
#define PB_ATT   38014
#define PB_BN    39374
#define PB_Z     39375
#define PB_DCT   39380

__global__ __launch_bounds__(256) void prep_all(
    const float* __restrict__ poses, ushort* __restrict__ pb16,
    const float* __restrict__ kw1, const float* __restrict__ qw1,
    ushort* __restrict__ Wt1k, ushort* __restrict__ Wt1q,
    const float* __restrict__ kw2, const float* __restrict__ qw2,
    ushort* __restrict__ Wt2k, ushort* __restrict__ Wt2q,
    const float* __restrict__ gc1_w, ushort* __restrict__ WT1,
    const float* __restrict__ gcb_w, ushort* __restrict__ WTb,
    const float* __restrict__ gc7_w, ushort* __restrict__ WT7,
    const float* __restrict__ gc1_att, const float* __restrict__ gcb_att,
    const float* __restrict__ gc7_att, ushort* __restrict__ att6,
    const float* __restrict__ bn1_g, const float* __restrict__ bn1_b,
    const float* __restrict__ gcb_g, const float* __restrict__ gcb_beta,
    float* __restrict__ bnT, float* __restrict__ zpadf, float* __restrict__ dct)
{
    const int blk = blockIdx.x;
    const int tid = threadIdx.x;
    if (blk < PB_POSES) {
        int idx = blk * 256 + tid;
        int i = idx % NODEP;
        int row = (idx / NODEP) % POSE_ROWS;
        int b = idx / (NODEP * POSE_ROWS);
        float v = (i < NF) ? poses[((long long)b * POSE_ROWS + row) * NF + i] * 1e-3f : 0.f;
        pb16[idx] = f2bf(v);
    } else if (blk < PB_K1B) {
        int wi = blk - PB_POSES;
        const float* src = (wi < 1664) ? kw1 : qw1;
        ushort* dst = (wi < 1664) ? Wt1k : Wt1q;
        int idx = (wi % 1664) * 256 + tid;
        int n = idx / 832, k = idx % 832;
        int h = k / 136, i = k % 136;
        float v = (i < 135 && h < 6) ? src[((long long)n * 135 + i) * 6 + h] : 0.f;
        dst[idx] = f2bf(v);
    } else if (blk < PB_K2B) {
        int wi = blk - PB_K1B;
        const float* src = (wi < 5120) ? kw2 : qw2;
        ushort* dst = (wi < 5120) ? Wt2k : Wt2q;
        int idx = (wi % 5120) * 256 + tid;
        int n = idx / 2560, k = idx % 2560;
        int h = k / 512, i = k % 512;
        dst[idx] = f2bf(src[((long long)n * 512 + i) * 5 + h]);
    } else if (blk < PB_WT1) {
        int idx = (blk - PB_K2B) * 256 + tid;      // 512*96
        int n = idx / 96, k = idx % 96;
        WT1[idx] = f2bf((k < 68) ? gc1_w[(long long)k * 512 + n] : 0.f);
    } else if (blk < PB_WTB) {
        int g = (blk - PB_WT1) * 256 + tid;
        int L = g >> 18, idx = g & 262143;
        int n = idx / 512, k = idx % 512;
        WTb[g] = f2bf(gcb_w[(long long)L * 262144 + (long long)k * 512 + n]);
    } else if (blk < PB_WT7) {
        int idx = (blk - PB_WTB) * 256 + tid;
        int n = idx / 512, k = idx % 512;
        WT7[idx] = f2bf(gc7_w[(long long)k * 68 + n]);
    } else if (blk < PB_ATT) {
        int wb = blk - PB_WT7;
        int mat = wb / 73;
        int idx = (wb % 73) * 256 + tid;
        if (idx < 18496) {
            int r = idx / 136, c = idx % 136;
            const float* src = (mat == 0) ? gc1_att : (mat == 5) ? gc7_att : (gcb_att + (mat - 1) * 18225);
            float v = (r < 135 && c < 135) ? src[r * 135 + c] : 0.f;
            att6[mat * 18496 + idx] = f2bf(v);
        }
    } else if (blk < PB_BN) {
        int g = (blk - PB_ATT) * 256 + tid;
        int p = g / 69632, idx = g % 69632;
        int node = idx % 136, m = idx / 136;
        const float* gs = (p == 0) ? bn1_g : (gcb_g + (p - 1) * 69120);
        const float* bs = (p == 0) ? bn1_b : (gcb_beta + (p - 1) * 69120);
        float* gt = bnT + (long long)p * 139264;
        float* bt = gt + 69632;
        gt[idx] = (node < 135) ? gs[node * 512 + m] : 0.f;
        bt[idx] = (node < 135) ? bs[node * 512 + m] : 0.f;
    } else if (blk < PB_Z) {
        if (tid < 128) zpadf[tid] = 0.f;
    } else {
        int idx = (blk - PB_Z) * 256 + tid;
        if (idx < DCTN * DCTN) {
            int k = idx / DCTN, i = idx % DCTN;
            double w = (k == 0) ? sqrt(1.0 / DCTN) : sqrt(2.0 / DCTN);
            dct[idx] = (float)(w * cos(3.14159265358979323846 * (i + 0.5) * k / (double)DCTN));
        }
    }
}

// ---------------- NT MFMA GEMM (LDS + global_load_lds, for the convs) ----------
template<int BM, int BN>
__global__ __launch_bounds__(256) void gemm2(
    const ushort* __restrict__ A, const ushort* __restrict__ Bt,
    const ushort* __restrict__ zpad,
    int M, int N, int K,
    int rpbA, long long sAw, long long sAr,
    long long sBr,
    float* __restrict__ C, ushort* __restrict__ C16,
    long long sCm, long long sCn, int do_relu)
{
    constexpr int SM = BM / 32, SN = BN / 32;
    constexpr int RA = BM / 32, RB = BN / 32;
    __shared__ ushort As[BM * 64];
    __shared__ ushort Bs[BN * 64];

    const int tid = threadIdx.x;
    const int lane = tid & 63, w = tid >> 6;
    const int m0 = blockIdx.y * BM, n0 = blockIdx.x * BN;
    const int wm = (w >> 1) * (BM / 2), wn = (w & 1) * (BN / 2);
    const int chunk = (lane & 7) ^ ((lane >> 3) & 7);

    const ushort* pA[RA]; int stA[RA];
    #pragma unroll
    for (int j = 0; j < RA; j++) {
        int m = m0 + j * 32 + w * 8 + (lane >> 3);
        bool v = m < M;
        long long off = v ? ((long long)(m / rpbA) * sAw + (long long)(m % rpbA) * sAr) : 0;
        pA[j] = v ? (A + off + chunk * 8) : (zpad + chunk * 8);
        stA[j] = v ? 64 : 0;
    }
    const ushort* pB[RB]; int stB[RB];
    #pragma unroll
    for (int j = 0; j < RB; j++) {
        int n = n0 + j * 32 + w * 8 + (lane >> 3);
        bool v = n < N;
        pB[j] = v ? (Bt + (long long)n * sBr + chunk * 8) : (zpad + chunk * 8);
        stB[j] = v ? 64 : 0;
    }

    floatx4 acc[SM][SN];
    #pragma unroll
    for (int i = 0; i < SM; i++)
        #pragma unroll
        for (int j = 0; j < SN; j++)
            acc[i][j] = (floatx4){0.f, 0.f, 0.f, 0.f};

    for (int k0 = 0; k0 < K; k0 += 64) {
        #pragma unroll
        for (int j = 0; j < RA; j++)
            GLOAD_LDS(pA[j], &As[(j * 32 + w * 8) * 64]);
        #pragma unroll
        for (int j = 0; j < RB; j++)
            GLOAD_LDS(pB[j], &Bs[(j * 32 + w * 8) * 64]);
        __syncthreads();

        #pragma unroll
        for (int kk = 0; kk < 2; kk++) {
            short8 af[SM], bf[SN];
            #pragma unroll
            for (int sm = 0; sm < SM; sm++) {
                int lr = wm + sm * 16 + (lane & 15);
                int slot = ((lane >> 4) + kk * 4) ^ (lr & 7);
                af[sm] = *(const short8*)&As[lr * 64 + slot * 8];
            }
            #pragma unroll
            for (int sn = 0; sn < SN; sn++) {
                int lr = wn + sn * 16 + (lane & 15);
                int slot = ((lane >> 4) + kk * 4) ^ (lr & 7);
                bf[sn] = *(const short8*)&Bs[lr * 64 + slot * 8];
            }
            #pragma unroll
            for (int sm = 0; sm < SM; sm++)
                #pragma unroll
                for (int sn = 0; sn < SN; sn++)
                    acc[sm][sn] = __builtin_amdgcn_mfma_f32_16x16x32_bf16(af[sm], bf[sn], acc[sm][sn], 0, 0, 0);
        }
        __syncthreads();

        #pragma unroll
        for (int j = 0; j < RA; j++) pA[j] += stA[j];
        #pragma unroll
        for (int j = 0; j < RB; j++) pB[j] += stB[j];
    }

    const int lc = lane & 15;
    const int lr4 = (lane >> 4) << 2;
    #pragma unroll
    for (int sm = 0; sm < SM; sm++) {
        #pragma unroll
        for (int sn = 0; sn < SN; sn++) {
            int n = n0 + wn + sn * 16 + lc;
            if (n >= N) continue;
            int mb = m0 + wm + sm * 16 + lr4;
            float vv[4];
            #pragma unroll
            for (int r = 0; r < 4; r++) {
                int m = mb + r;
                float v = acc[sm][sn][r];
                if (do_relu) v = fmaxf(v, 0.f);
                vv[r] = v;
                if (m < M && C) C[(long long)m * sCm + (long long)n * sCn] = v;
            }
            if (C16 && mb + 3 < M) {
                ushort4 pk;
                pk.x = f2bf(vv[0]); pk.y = f2bf(vv[1]); pk.z = f2bf(vv[2]); pk.w = f2bf(vv[3]);
                *(ushort4*)&C16[(long long)mb * sCm + (long long)n * sCn] = pk;
            }
        }
    }
}

// ---------------- fused persistent GCN: one block per sample ----------------
// y^T layout in global: buf[f * RP + b*136 + node] (bf16).
// Per layer: mix z = att @ y  (z in LDS, [node 144][f 512], XOR-swizzled 16B chunks),
// then out = W^T @ z + bias (+bn,tanh,resid) -> global y^T ping-pong.
__global__ __launch_bounds__(512) void gcn_all(
    const ushort* __restrict__ xT, ushort* __restrict__ bufA, ushort* __restrict__ bufB,
    const ushort* __restrict__ WT1, const ushort* __restrict__ WTb, const ushort* __restrict__ WT7,
    const ushort* __restrict__ att6, const float* __restrict__ bnT,
    const float* __restrict__ gc1_b, const float* __restrict__ gcb_b, const float* __restrict__ gc7_b,
    float* __restrict__ h32)
{
    extern __shared__ ushort zs[];                 // 144 * 512 bf16 = 147456 B
    const int b = blockIdx.x;
    const int tid = threadIdx.x;
    const int wv = tid >> 6;                       // 0..7
    const int lane = tid & 63;
    const int lc = lane & 15;
    const int kq = lane >> 4;                      // 0..3
    const int lr4 = kq << 2;
    const long long boff = (long long)b * 136;

    for (int L = 0; L < 6; L++) {
        const ushort* inb; ushort* outb; const ushort* residb;
        const ushort* Wp; int KS, KWs, FT;
        const float* bias; const float* bng;
        const ushort* attL = att6 + L * 18496;
        if (L == 0)      { inb = xT;  outb = bufA; residb = nullptr; Wp = WT1; KS = 3;  KWs = 96;  FT = 6;
                           bias = gc1_b; bng = bnT; }
        else if (L == 5) { inb = bufA; outb = nullptr; residb = nullptr; Wp = WT7; KS = 16; KWs = 512; FT = 32;
                           bias = gc7_b; bng = nullptr; }
        else             { inb = (L & 1) ? bufA : bufB; outb = (L & 1) ? bufB : bufA;
                           residb = (L == 2 || L == 4) ? outb : nullptr;
                           Wp = WTb + (L - 1) * 262144; KS = 16; KWs = 512; FT = 32;
                           bias = gcb_b + (L - 1) * 512; bng = bnT + (long long)L * 139264; }

        // ---------- MIX: z[node][f] = sum_n' att[node,n'] * in[f][n'] ----------
        for (int g = 0; g < 3; g++) {
            short8 afr[3][5];
            #pragma unroll
            for (int mm = 0; mm < 3; mm++) {
                int mrow = g * 48 + mm * 16 + lc;
                if (mrow > 135) mrow = 135;
                const ushort* ab = attL + mrow * 136;
                #pragma unroll
                for (int ks = 0; ks < 5; ks++) {
                    if (ks < 4 || kq == 0)
                        afr[mm][ks] = *(const short8*)(ab + ks * 32 + kq * 8);
                    else
                        afr[mm][ks] = (short8){0,0,0,0,0,0,0,0};
                }
            }
            for (int ft = wv; ft < FT; ft += 8) {
                const ushort* bb = inb + (long long)(ft * 16 + lc) * RP + boff + kq * 8;
                floatx4 a0 = {0.f,0.f,0.f,0.f}, a1 = a0, a2 = a0;
                #pragma unroll
                for (int ks = 0; ks < 5; ks++) {
                    short8 bfr = *(const short8*)(bb + ks * 32);
                    a0 = __builtin_amdgcn_mfma_f32_16x16x32_bf16(afr[0][ks], bfr, a0, 0, 0, 0);
                    a1 = __builtin_amdgcn_mfma_f32_16x16x32_bf16(afr[1][ks], bfr, a1, 0, 0, 0);
                    a2 = __builtin_amdgcn_mfma_f32_16x16x32_bf16(afr[2][ks], bfr, a2, 0, 0, 0);
                }
                int f = ft * 16 + lc;
                int c = f >> 3;
                #pragma unroll
                for (int mm = 0; mm < 3; mm++) {
                    floatx4 av = (mm == 0) ? a0 : (mm == 1) ? a1 : a2;
                    #pragma unroll
                    for (int r = 0; r < 4; r++) {
                        int node = g * 48 + mm * 16 + lr4 + r;
                        int cs = (c & 56) | ((c ^ node) & 7);
                        zs[node * 512 + cs * 8 + (f & 7)] = f2bf(av[r]);
                    }
                }
            }
        }
        __syncthreads();

        // ---------- H: out[fo][node] = sum_fi W[fo][fi] * z[node][fi] ----------
        for (int ng = 0; ng < 2; ng++) {
            const int nbase = ng * 5;
            const int ncnt = ng ? 4 : 5;
            floatx4 acc[4][5];
            #pragma unroll
            for (int mm = 0; mm < 4; mm++)
                #pragma unroll
                for (int nn = 0; nn < 5; nn++)
                    acc[mm][nn] = (floatx4){0.f, 0.f, 0.f, 0.f};

            for (int ks = 0; ks < KS; ks++) {
                short8 afr[4];
                #pragma unroll
                for (int mm = 0; mm < 4; mm++) {
                    int fo = (wv * 4 + mm) * 16 + lc;
                    if (L == 5 && fo > 67) fo = 67;
                    afr[mm] = *(const short8*)(Wp + (long long)fo * KWs + ks * 32 + kq * 8);
                }
                #pragma unroll
                for (int nn = 0; nn < 5; nn++) {
                    if (nn >= ncnt) continue;
                    int n = (nbase + nn) * 16 + lc;
                    int c = ks * 4 + kq;
                    int cs = (c & 56) | ((c ^ n) & 7);
                    short8 bfr = *(const short8*)&zs[n * 512 + cs * 8];
                    #pragma unroll
                    for (int mm = 0; mm < 4; mm++)
                        acc[mm][nn] = __builtin_amdgcn_mfma_f32_16x16x32_bf16(afr[mm], bfr, acc[mm][nn], 0, 0, 0);
                }
            }
            // epilogue
            #pragma unroll
            for (int mm = 0; mm < 4; mm++) {
                #pragma unroll
                for (int nn = 0; nn < 5; nn++) {
                    if (nn >= ncnt) continue;
                    int node = (nbase + nn) * 16 + lc;
                    if (node >= 136) continue;
                    int fobase = (wv * 4 + mm) * 16 + lr4;
                    #pragma unroll
                    for (int r = 0; r < 4; r++) {
                        int fo = fobase + r;
                        float v = acc[mm][nn][r];
                        long long addr = (long long)fo * RP + boff + node;
                        if (L == 5) {
                            if (fo < 68) {
                                v += bias[fo];
                                v += bf2f(xT[addr]);
                                h32[(boff + node) * 68 + fo] = v;
                            }
                        } else {
                            v += bias[fo];
                            long long gi = (long long)fo * 136 + node;
                            v = bng[gi] * (v * BN_SCALE) + bng[69632 + gi];
                            v = tanh_fast(v);
                            if (residb) v += bf2f(residb[addr]);
                            outb[addr] = f2bf(v);
                        }
                    }
                }
            }
        }
        __syncthreads();
    }
}

// ---------------- attention scores + normalize ----------------
__global__ __launch_bounds__(256) void att_k(const float* __restrict__ kf, const float* __restrict__ qf,
                                             float* __restrict__ att) {
    int b = blockIdx.x;
    int tid = threadIdx.x;
    int lane = tid & 63, w = tid >> 6;
    __shared__ float s[96];
    __shared__ float ssum;
    const float* qb = qf + b * DD + lane * 8;
    float4 q0 = *(const float4*)qb;
    float4 q1 = *(const float4*)(qb + 4);
    const float* kb = kf + (long long)b * VN * DD;
    for (int v = w; v < VN; v += 4) {
        const float* kr = kb + v * DD + lane * 8;
        float4 k0 = *(const float4*)kr;
        float4 k1 = *(const float4*)(kr + 4);
        float p = q0.x * k0.x + q0.y * k0.y + q0.z * k0.z + q0.w * k0.w
                + q1.x * k1.x + q1.y * k1.y + q1.z * k1.z + q1.w * k1.w;
        #pragma unroll
        for (int off = 32; off; off >>= 1) p += __shfl_xor(p, off);
        if (lane == 0) s[v] = p + 1e-15f;
    }
    __syncthreads();
    if (tid < 64) {
        float p2 = (tid < VN ? s[tid] : 0.f) + ((tid + 64) < VN ? s[tid + 64] : 0.f);
        #pragma unroll
        for (int off = 32; off; off >>= 1) p2 += __shfl_xor(p2, off);
        if (tid == 0) ssum = p2;
    }
    __syncthreads();
    float inv = 1.f / ssum;
    for (int v = tid; v < VN; v += 256) att[b * VN + v] = s[v] * inv;
}

// ---------------- w34[b,t,f] = sum_v att[b,v] * poses[b,v+t,f] ----------------
__global__ void weighted_k(const float* __restrict__ poses, const float* __restrict__ att,
                           float* __restrict__ w34) {
    int t = blockIdx.x;
    int b = blockIdx.y;
    int f = threadIdx.x;
    if (f >= NF) return;
    const float* pb = poses + (long long)b * POSE_ROWS * NF + t * NF + f;
    const float* ab = att + b * VN;
    float acc = 0.f;
    for (int v = 0; v < VN; v++) acc += ab[v] * pb[v * NF];
    w34[(long long)b * DCTN * NF + t * NF + f] = acc;
}

// ---------------- x = concat(dct_in, dct_att) -> feature-major bf16 x^T ----
__global__ void build_x(const float* __restrict__ poses, const float* __restrict__ w34,
                        const float* __restrict__ dctm, ushort* __restrict__ xT16) {
    int idx = blockIdx.x * 256 + threadIdx.x;
    if (idx >= BATCH * NF * 68) return;
    int kk = idx % 68;
    int f = (idx / 68) % NF;
    int b = idx / (68 * NF);
    float acc = 0.f;
    if (kk < DCTN) {
        const float* pb = poses + (long long)b * POSE_ROWS * NF;
        #pragma unroll
        for (int t = 0; t < DCTN; t++) {
            int row = (t < KQ) ? (INN - KQ + t) : (INN - 1);
            acc += dctm[kk * DCTN + t] * pb[row * NF + f];
        }
    } else {
        int k2 = kk - DCTN;
        const float* wb = w34 + (long long)b * DCTN * NF + f;
        #pragma unroll
        for (int t = 0; t < DCTN; t++) acc += dctm[k2 * DCTN + t] * wb[t * NF];
    }
    xT16[(long long)kk * RP + (long long)b * NODEP + f] = f2bf(acc);
}

// ---------------- preds ----------------
__global__ void idct_out(const float* __restrict__ h32, const float* __restrict__ dctm,
                         float* __restrict__ out) {
    int idx = blockIdx.x * 256 + threadIdx.x;
    if (idx >= BATCH * OUTN * NF) return;
    int f = idx % NF;
    int t = (idx / NF) % OUTN;
    int b = idx / (NF * OUTN);
    const float* yr = h32 + ((long long)b * NODEP + f) * 68;
    float acc = 0.f;
    #pragma unroll
    for (int k = 0; k < DCTN; k++) acc += dctm[k * DCTN + (KQ + t)] * yr[k];
    out[idx] = acc;
}

// ---------------- host ----------------
extern "C" void kernel_launch(void* const* d_in, const int* in_sizes, int n_in,
                              void* d_out, int out_size, void* d_ws, size_t ws_size,
                              hipStream_t stream) {
    const float* poses   = (const float*)d_in[0];
    const float* qw1     = (const float*)d_in[1];
    const float* qw2     = (const float*)d_in[2];
    const float* kw1     = (const float*)d_in[3];
    const float* kw2     = (const float*)d_in[4];
    const float* gc1_att = (const float*)d_in[5];
    const float* gc1_w   = (const float*)d_in[6];
    const float* gc1_b   = (const float*)d_in[7];
    const float* bn1_g   = (const float*)d_in[8];
    const float* bn1_b   = (const float*)d_in[9];
    const float* gcb_att = (const float*)d_in[10];
    const float* gcb_w   = (const float*)d_in[11];
    const float* gcb_b   = (const float*)d_in[12];
    const float* gcb_g   = (const float*)d_in[13];
    const float* gcb_beta= (const float*)d_in[14];
    const float* gc7_att = (const float*)d_in[15];
    const float* gc7_w   = (const float*)d_in[16];
    const float* gc7_b   = (const float*)d_in[17];
    float* out = (float*)d_out;
    float* w = (float*)d_ws;

    // ---- workspace layout (f32 units) ----
    float* dct   = w;                      // 1156 -> 1280
    float* att   = w + 1280;               // -> 23808
    float* w34   = w + 23808;              // -> 1198848
    float* h32   = w + 3566336;            // RP*68 -> 5933824
    float* qf    = w + 5933824;            // -> 6064896
    ushort* su   = (ushort*)(w + 6064896); // bf16 weight region
    ushort* WT1   = su;                    // 512*96  = 49152
    ushort* WTb   = su + 49152;            // 1048576
    ushort* WT7   = su + 1097728;          // 34816
    ushort* att6  = su + 1132544;          // 6*18496 = 110976 -> end 1243520u
    float* bnT   = w + 6717120;            // 5 * 139264 -> 7413440
    float* kf    = w + 7413440;            // -> 18816704
    ushort* R2   = (ushort*)(w + 18816704);// 17825792 u
    ushort* yT16  = R2;                    // bufA
    ushort* r1k16 = R2;                    // phase-A alias
    ushort* r1q16 = R2 + 11927552;
    ushort* R3   = (ushort*)(w + 27729600);// 17825792 u
    ushort* hT16  = R3;                    // bufB
    ushort* pb16  = R3;                    // phase-A alias
    ushort* Wt1k  = R3 + 5013504;
    ushort* Wt1q  = R3 + 5439488;
    ushort* Wt2k  = R3 + 5865472;
    ushort* Wt2q  = R3 + 7176192;
    ushort* R4   = (ushort*)(w + 36642496);
    ushort* xT16  = R4;                    // 68 rows x RP
    float* zpadf = w + 45555392;           // zero page
    const ushort* zpad = (const ushort*)zpadf;

    // allow 147456 B dynamic LDS for gcn_all (idempotent, host-side only)
    hipFuncSetAttribute((const void*)gcn_all, hipFuncAttributeMaxDynamicSharedMemorySize, 147456);

    // ---- fused prep ----
    prep_all<<<PB_DCT, 256, 0, stream>>>(
        poses, pb16, kw1, qw1, Wt1k, Wt1q, kw2, qw2, Wt2k, Wt2q,
        gc1_w, WT1, gcb_w, WTb, gc7_w, WT7,
        gc1_att, gcb_att, gc7_att, att6,
        bn1_g, bn1_b, gcb_g, gcb_beta, bnT, zpadf, dct);

    // ---- conv stack (proven R5 config) ----
    gemm2<128,128><<<dim3(4, 182, 1), 256, 0, stream>>>(pb16, Wt1k, zpad, 23296, 512, 832,
        91, 19584LL, 136LL, 832LL, (float*)nullptr, r1k16, 512LL, 1LL, 1);
    gemm2<128,128><<<dim3(4, 10, 1), 256, 0, stream>>>(pb16 + 110*136, Wt1q, zpad, 1280, 512, 832,
        5, 19584LL, 136LL, 832LL, (float*)nullptr, r1q16, 512LL, 1LL, 1);
    gemm2<128,128><<<dim3(4, 174, 1), 256, 0, stream>>>(r1k16, Wt2k, zpad, 22272, 512, 2560,
        87, 46592LL, 512LL, 2560LL, kf, (ushort*)nullptr, 512LL, 1LL, 1);
    gemm2<64,64><<<dim3(8, 4, 1), 256, 0, stream>>>(r1q16, Wt2q, zpad, 256, 512, 2560,
        1 << 30, 0LL, 2560LL, 2560LL, qf, (ushort*)nullptr, 512LL, 1LL, 1);

    // ---- attention + x ----
    att_k<<<BATCH, 256, 0, stream>>>(kf, qf, att);
    weighted_k<<<dim3(DCTN, BATCH), 192, 0, stream>>>(poses, att, w34);
    build_x<<<(BATCH * NF * 68 + 255) / 256, 256, 0, stream>>>(poses, w34, dct, xT16);

    // ---- fused GCN: gc1 + 4 residual layers + gc7, one dispatch ----
    gcn_all<<<BATCH, 512, 147456, stream>>>(
        xT16, yT16, hT16, WT1, WTb, WT7, att6, bnT, gc1_b, gcb_b, gc7_b, h32);

    idct_out<<<(BATCH * OUTN * NF + 255) / 256, 256, 0, stream>>>(h32, dct, out);
}

// Round 9
// 1028.209 us; speedup vs baseline: 1.7261x; 1.2365x over previous
//
#include <hip/hip_runtime.h>
#include <math.h>

// ---------------- problem constants ----------------
#define POSE_ROWS 144
#define NF 135
#define DD 512
#define KQ 10
#define DCTN 34
#define INN 120
#define OUTN 24
#define VN 87
#define BATCH 256
#define RP 34816              // padded row dim: 256 * 136
#define NODEP 136
#define BN_SCALE 0.9999950000374997f

typedef __attribute__((ext_vector_type(8))) short short8;
typedef __attribute__((ext_vector_type(4))) float floatx4;

static __device__ __forceinline__ ushort f2bf(float f) {
    unsigned u = __builtin_bit_cast(unsigned, f);
    u = (u + 0x7FFFu + ((u >> 16) & 1u)) >> 16;
    return (ushort)u;
}
static __device__ __forceinline__ float bf2f(ushort s) {
    return __builtin_bit_cast(float, (unsigned)s << 16);
}
// fast tanh via exp2
static __device__ __forceinline__ float tanh_fast(float x) {
    float ax = __builtin_fabsf(x);
    float e = __builtin_amdgcn_exp2f(ax * -2.885390081777927f);   // e^{-2ax}
    float t = (1.f - e) * __builtin_amdgcn_rcpf(1.f + e);
    return __builtin_copysignf(t, x);
}

#define GLOAD_LDS(gp, lp) __builtin_amdgcn_global_load_lds( \
    (const __attribute__((address_space(1))) unsigned int*)(const void*)(gp), \
    (__attribute__((address_space(3))) unsigned int*)(void*)(lp), 16, 0, 0)

// ---------------- fused prep kernel (all weight repacks / converts in ONE dispatch) ----
#define PB_POSES 19584
#define PB_K1B   22912
#define PB_K2B   33152
#define PB_WT1   33408
#define PB_WTB   37504
#define PB_WT7   37640
#define PB_A1    37742
#define PB_AB    38147
#define PB_A7    38249
#define PB_BN    39609
#define PB_Z     39610
#define PB_DCT   39615

__global__ __launch_bounds__(256) void prep_all(
    const float* __restrict__ poses, ushort* __restrict__ pb16,
    const float* __restrict__ kw1, const float* __restrict__ qw1,
    ushort* __restrict__ Wt1k, ushort* __restrict__ Wt1q,
    const float* __restrict__ kw2, const float* __restrict__ qw2,
    ushort* __restrict__ Wt2k, ushort* __restrict__ Wt2q,
    const float* __restrict__ gc1_w, ushort* __restrict__ WT1,
    const float* __restrict__ gcb_w, ushort* __restrict__ WTb,
    const float* __restrict__ gc7_w, ushort* __restrict__ WT7,
    const float* __restrict__ gc1_att, ushort* __restrict__ A16_1,
    const float* __restrict__ gcb_att, ushort* __restrict__ A16_B,
    const float* __restrict__ gc7_att, ushort* __restrict__ A16_7,
    const float* __restrict__ bn1_g, const float* __restrict__ bn1_b,
    const float* __restrict__ gcb_g, const float* __restrict__ gcb_beta,
    float* __restrict__ bnT, float* __restrict__ zpadf, float* __restrict__ dct)
{
    const int blk = blockIdx.x;
    const int tid = threadIdx.x;
    if (blk < PB_POSES) {
        int idx = blk * 256 + tid;
        int i = idx % NODEP;
        int row = (idx / NODEP) % POSE_ROWS;
        int b = idx / (NODEP * POSE_ROWS);
        float v = (i < NF) ? poses[((long long)b * POSE_ROWS + row) * NF + i] * 1e-3f : 0.f;
        pb16[idx] = f2bf(v);
    } else if (blk < PB_K1B) {
        int wi = blk - PB_POSES;
        const float* src = (wi < 1664) ? kw1 : qw1;
        ushort* dst = (wi < 1664) ? Wt1k : Wt1q;
        int idx = (wi % 1664) * 256 + tid;
        int n = idx / 832, k = idx % 832;
        int h = k / 136, i = k % 136;
        float v = (i < 135 && h < 6) ? src[((long long)n * 135 + i) * 6 + h] : 0.f;
        dst[idx] = f2bf(v);
    } else if (blk < PB_K2B) {
        int wi = blk - PB_K1B;
        const float* src = (wi < 5120) ? kw2 : qw2;
        ushort* dst = (wi < 5120) ? Wt2k : Wt2q;
        int idx = (wi % 5120) * 256 + tid;
        int n = idx / 2560, k = idx % 2560;
        int h = k / 512, i = k % 512;
        dst[idx] = f2bf(src[((long long)n * 512 + i) * 5 + h]);
    } else if (blk < PB_WT1) {
        int idx = (blk - PB_K2B) * 256 + tid;
        int n = idx / 128, k = idx % 128;
        WT1[idx] = f2bf((k < 68) ? gc1_w[(long long)k * 512 + n] : 0.f);
    } else if (blk < PB_WTB) {
        int g = (blk - PB_WT1) * 256 + tid;
        int L = g >> 18, idx = g & 262143;
        int n = idx / 512, k = idx % 512;
        WTb[g] = f2bf(gcb_w[(long long)L * 262144 + (long long)k * 512 + n]);
    } else if (blk < PB_WT7) {
        int idx = (blk - PB_WTB) * 256 + tid;
        int n = idx / 512, k = idx % 512;
        WT7[idx] = f2bf(gc7_w[(long long)k * 68 + n]);
    } else if (blk < PB_A1) {
        int idx = (blk - PB_WT7) * 256 + tid;
        if (idx < 135 * 192) {
            int r = idx / 192, c = idx % 192;
            A16_1[idx] = f2bf(c < 135 ? gc1_att[r * 135 + c] : 0.f);
        }
    } else if (blk < PB_AB) {
        int idx = (blk - PB_A1) * 256 + tid;
        int r = idx / 192, c = idx % 192;
        A16_B[idx] = f2bf(c < 135 ? gcb_att[r * 135 + c] : 0.f);
    } else if (blk < PB_A7) {
        int idx = (blk - PB_AB) * 256 + tid;
        if (idx < 135 * 192) {
            int r = idx / 192, c = idx % 192;
            A16_7[idx] = f2bf(c < 135 ? gc7_att[r * 135 + c] : 0.f);
        }
    } else if (blk < PB_BN) {
        int g = (blk - PB_A7) * 256 + tid;
        int p = g / 69632, idx = g % 69632;
        int node = idx % 136, m = idx / 136;
        const float* gs = (p == 0) ? bn1_g : (gcb_g + (p - 1) * 69120);
        const float* bs = (p == 0) ? bn1_b : (gcb_beta + (p - 1) * 69120);
        float* gt = bnT + (long long)p * 139264;
        float* bt = gt + 69632;
        gt[idx] = (node < 135) ? gs[node * 512 + m] : 0.f;
        bt[idx] = (node < 135) ? bs[node * 512 + m] : 0.f;
    } else if (blk < PB_Z) {
        if (tid < 128) zpadf[tid] = 0.f;
    } else {
        int idx = (blk - PB_Z) * 256 + tid;
        if (idx < DCTN * DCTN) {
            int k = idx / DCTN, i = idx % DCTN;
            double w = (k == 0) ? sqrt(1.0 / DCTN) : sqrt(2.0 / DCTN);
            dct[idx] = (float)(w * cos(3.14159265358979323846 * (i + 0.5) * k / (double)DCTN));
        }
    }
}

// ---------------- NT MFMA GEMM, BK=64, global_load_lds staging, XOR-swizzled LDS ----------
// XCD-aware block mapping:
//   mode 0: mb = blockIdx.y, nb = blockIdx.x
//   mode 1: n-partitioned per XCD (stream = B): x=gx&7; s=gx>>3; mb=s%CNT; nb=x*Pc+s/CNT
//   mode 2: m-partitioned per XCD (stream = A): x=gx&7; s=gx>>3; nb=s%CNT; mb=x*Pc+s/CNT
template<int BM, int BN>
__global__ __launch_bounds__(256) void gemm2(
    const ushort* __restrict__ A, const ushort* __restrict__ Bt,
    const ushort* __restrict__ zpad,
    int M, int N, int K,
    int mode, int CNT, int Pc,
    int rpbA, long long sAw, long long sAr, long long sAbz,
    long long sBr, long long sBbz,
    float* __restrict__ C, ushort* __restrict__ C16,
    long long sCbz, long long sCm, long long sCn,
    int do_relu, const float* __restrict__ bias, int bias_mode,
    const float* __restrict__ bnTg, const float* __restrict__ bnTb,
    int do_tanh, const ushort* __restrict__ resid16, const float* __restrict__ resid32)
{
    constexpr int SM = BM / 32, SN = BN / 32;
    constexpr int RA = BM / 32, RB = BN / 32;     // staging rounds, 32 rows each
    __shared__ ushort As[BM * 64];
    __shared__ ushort Bs[BN * 64];

    int mb, nb;
    if (mode == 0) { mb = blockIdx.y; nb = blockIdx.x; }
    else {
        int gx = blockIdx.x;
        int x = gx & 7, s = gx >> 3;
        if (mode == 1) { mb = s % CNT; nb = x * Pc + s / CNT; }
        else           { nb = s % CNT; mb = x * Pc + s / CNT; }
    }
    const int m0 = mb * BM, n0 = nb * BN;
    if (m0 >= M || n0 >= N) return;          // block-uniform: safe before barriers

    const int tid = threadIdx.x;
    const int lane = tid & 63, w = tid >> 6;
    const int bz = blockIdx.z;
    const int wm = (w >> 1) * (BM / 2), wn = (w & 1) * (BN / 2);
    const int chunk = (lane & 7) ^ ((lane >> 3) & 7);

    const ushort* pA[RA]; int stA[RA];
    #pragma unroll
    for (int j = 0; j < RA; j++) {
        int m = m0 + j * 32 + w * 8 + (lane >> 3);
        bool v = m < M;
        long long off = v ? ((long long)(m / rpbA) * sAw + (long long)(m % rpbA) * sAr
                            + (long long)bz * sAbz) : 0;
        pA[j] = v ? (A + off + chunk * 8) : (zpad + chunk * 8);
        stA[j] = v ? 64 : 0;
    }
    const ushort* pB[RB]; int stB[RB];
    #pragma unroll
    for (int j = 0; j < RB; j++) {
        int n = n0 + j * 32 + w * 8 + (lane >> 3);
        bool v = n < N;
        long long off = v ? ((long long)n * sBr + (long long)bz * sBbz) : 0;
        pB[j] = v ? (Bt + off + chunk * 8) : (zpad + chunk * 8);
        stB[j] = v ? 64 : 0;
    }

    floatx4 acc[SM][SN];
    #pragma unroll
    for (int i = 0; i < SM; i++)
        #pragma unroll
        for (int j = 0; j < SN; j++)
            acc[i][j] = (floatx4){0.f, 0.f, 0.f, 0.f};

    for (int k0 = 0; k0 < K; k0 += 64) {
        #pragma unroll
        for (int j = 0; j < RA; j++)
            GLOAD_LDS(pA[j], &As[(j * 32 + w * 8) * 64]);
        #pragma unroll
        for (int j = 0; j < RB; j++)
            GLOAD_LDS(pB[j], &Bs[(j * 32 + w * 8) * 64]);
        __syncthreads();

        #pragma unroll
        for (int kk = 0; kk < 2; kk++) {
            short8 af[SM], bf[SN];
            #pragma unroll
            for (int sm = 0; sm < SM; sm++) {
                int lr = wm + sm * 16 + (lane & 15);
                int slot = ((lane >> 4) + kk * 4) ^ (lr & 7);
                af[sm] = *(const short8*)&As[lr * 64 + slot * 8];
            }
            #pragma unroll
            for (int sn = 0; sn < SN; sn++) {
                int lr = wn + sn * 16 + (lane & 15);
                int slot = ((lane >> 4) + kk * 4) ^ (lr & 7);
                bf[sn] = *(const short8*)&Bs[lr * 64 + slot * 8];
            }
            #pragma unroll
            for (int sm = 0; sm < SM; sm++)
                #pragma unroll
                for (int sn = 0; sn < SN; sn++)
                    acc[sm][sn] = __builtin_amdgcn_mfma_f32_16x16x32_bf16(af[sm], bf[sn], acc[sm][sn], 0, 0, 0);
        }
        __syncthreads();

        #pragma unroll
        for (int j = 0; j < RA; j++) pA[j] += stA[j];
        #pragma unroll
        for (int j = 0; j < RB; j++) pB[j] += stB[j];
    }

    // epilogue: D mapping col(n)=lane&15, row(m)=(lane>>4)*4+r
    const int lc = lane & 15;
    const int lr4 = (lane >> 4) << 2;
    #pragma unroll
    for (int sm = 0; sm < SM; sm++) {
        #pragma unroll
        for (int sn = 0; sn < SN; sn++) {
            int n = n0 + wn + sn * 16 + lc;
            if (n >= N) continue;
            int node = n % 136;
            int mbv = m0 + wm + sm * 16 + lr4;
            float vv[4];
            #pragma unroll
            for (int r = 0; r < 4; r++) {
                int m = mbv + r;
                float v = acc[sm][sn][r];
                if (do_relu) v = fmaxf(v, 0.f);
                if (bias) v += (bias_mode == 1) ? bias[m < M ? m : 0] : bias[n];
                if (bnTg) {
                    long long gi = (long long)(m < M ? m : 0) * 136 + node;
                    v = bnTg[gi] * (v * BN_SCALE) + bnTb[gi];
                }
                if (do_tanh) v = tanh_fast(v);
                long long addr = (long long)bz * sCbz + (long long)m * sCm + (long long)n * sCn;
                if (m < M) {
                    if (resid16) v += bf2f(resid16[addr]);
                    else if (resid32) v += resid32[addr];
                    if (C) C[addr] = v;
                    if (C16 && sCm != 1) C16[addr] = f2bf(v);
                }
                vv[r] = v;
            }
            if (C16 && sCm == 1 && mbv + 3 < M) {
                ushort4 pk;
                pk.x = f2bf(vv[0]); pk.y = f2bf(vv[1]); pk.z = f2bf(vv[2]); pk.w = f2bf(vv[3]);
                *(ushort4*)&C16[(long long)bz * sCbz + mbv + (long long)n * sCn] = pk;
            }
        }
    }
}

// ---------------- attention scores + normalize (wave-parallel) ----------------
__global__ __launch_bounds__(256) void att_k(const float* __restrict__ kf, const float* __restrict__ qf,
                                             float* __restrict__ att) {
    int b = blockIdx.x;
    int tid = threadIdx.x;
    int lane = tid & 63, w = tid >> 6;
    __shared__ float s[96];
    __shared__ float ssum;
    const float* qb = qf + b * DD + lane * 8;
    float4 q0 = *(const float4*)qb;
    float4 q1 = *(const float4*)(qb + 4);
    const float* kb = kf + (long long)b * VN * DD;
    for (int v = w; v < VN; v += 4) {
        const float* kr = kb + v * DD + lane * 8;
        float4 k0 = *(const float4*)kr;
        float4 k1 = *(const float4*)(kr + 4);
        float p = q0.x * k0.x + q0.y * k0.y + q0.z * k0.z + q0.w * k0.w
                + q1.x * k1.x + q1.y * k1.y + q1.z * k1.z + q1.w * k1.w;
        #pragma unroll
        for (int off = 32; off; off >>= 1) p += __shfl_xor(p, off);
        if (lane == 0) s[v] = p + 1e-15f;
    }
    __syncthreads();
    if (tid < 64) {
        float p2 = (tid < VN ? s[tid] : 0.f) + ((tid + 64) < VN ? s[tid + 64] : 0.f);
        #pragma unroll
        for (int off = 32; off; off >>= 1) p2 += __shfl_xor(p2, off);
        if (tid == 0) ssum = p2;
    }
    __syncthreads();
    float inv = 1.f / ssum;
    for (int v = tid; v < VN; v += 256) att[b * VN + v] = s[v] * inv;
}

// ---------------- w34[b,t,f] = sum_v att[b,v] * poses[b,v+t,f] ----------------
__global__ void weighted_k(const float* __restrict__ poses, const float* __restrict__ att,
                           float* __restrict__ w34) {
    int t = blockIdx.x;
    int b = blockIdx.y;
    int f = threadIdx.x;
    if (f >= NF) return;
    const float* pb = poses + (long long)b * POSE_ROWS * NF + t * NF + f;
    const float* ab = att + b * VN;
    float acc = 0.f;
    for (int v = 0; v < VN; v++) acc += ab[v] * pb[v * NF];
    w34[(long long)b * DCTN * NF + t * NF + f] = acc;
}

// ---------------- x = concat(dct_in, dct_att); node-major f32 + feature-major bf16 ----
__global__ void build_x(const float* __restrict__ poses, const float* __restrict__ w34,
                        const float* __restrict__ dctm, float* __restrict__ x32,
                        ushort* __restrict__ xT16) {
    int idx = blockIdx.x * 256 + threadIdx.x;
    if (idx >= BATCH * NF * 68) return;
    int kk = idx % 68;
    int f = (idx / 68) % NF;
    int b = idx / (68 * NF);
    float acc = 0.f;
    if (kk < DCTN) {
        const float* pb = poses + (long long)b * POSE_ROWS * NF;
        #pragma unroll
        for (int t = 0; t < DCTN; t++) {
            int row = (t < KQ) ? (INN - KQ + t) : (INN - 1);
            acc += dctm[kk * DCTN + t] * pb[row * NF + f];
        }
    } else {
        int k2 = kk - DCTN;
        const float* wb = w34 + (long long)b * DCTN * NF + f;
        #pragma unroll
        for (int t = 0; t < DCTN; t++) acc += dctm[k2 * DCTN + t] * wb[t * NF];
    }
    long long R = (long long)b * NODEP + f;
    x32[R * 68 + kk] = acc;
    xT16[(long long)kk * RP + R] = f2bf(acc);
}

// ---------------- preds[b,t,f] = sum_k dct[k][10+t] * h32[(b*136+f)*68+k] ----------------
__global__ void idct_out(const float* __restrict__ h32, const float* __restrict__ dctm,
                         float* __restrict__ out) {
    int idx = blockIdx.x * 256 + threadIdx.x;
    if (idx >= BATCH * OUTN * NF) return;
    int f = idx % NF;
    int t = (idx / NF) % OUTN;
    int b = idx / (NF * OUTN);
    const float* yr = h32 + ((long long)b * NODEP + f) * 68;
    float acc = 0.f;
    #pragma unroll
    for (int k = 0; k < DCTN; k++) acc += dctm[k * DCTN + (KQ + t)] * yr[k];
    out[idx] = acc;
}

// ---------------- host ----------------
extern "C" void kernel_launch(void* const* d_in, const int* in_sizes, int n_in,
                              void* d_out, int out_size, void* d_ws, size_t ws_size,
                              hipStream_t stream) {
    const float* poses   = (const float*)d_in[0];
    const float* qw1     = (const float*)d_in[1];
    const float* qw2     = (const float*)d_in[2];
    const float* kw1     = (const float*)d_in[3];
    const float* kw2     = (const float*)d_in[4];
    const float* gc1_att = (const float*)d_in[5];
    const float* gc1_w   = (const float*)d_in[6];
    const float* gc1_b   = (const float*)d_in[7];
    const float* bn1_g   = (const float*)d_in[8];
    const float* bn1_b   = (const float*)d_in[9];
    const float* gcb_att = (const float*)d_in[10];
    const float* gcb_w   = (const float*)d_in[11];
    const float* gcb_b   = (const float*)d_in[12];
    const float* gcb_g   = (const float*)d_in[13];
    const float* gcb_beta= (const float*)d_in[14];
    const float* gc7_att = (const float*)d_in[15];
    const float* gc7_w   = (const float*)d_in[16];
    const float* gc7_b   = (const float*)d_in[17];
    float* out = (float*)d_out;
    float* w = (float*)d_ws;

    // ---- workspace layout (f32 units) ----
    float* dct   = w;                      // 1156 -> pad 1280
    float* att   = w + 1280;               // -> 23808
    float* w34   = w + 23808;              // -> 1198848
    float* x32   = w + 1198848;            // RP*68 -> 3566336
    float* h32   = w + 3566336;            // RP*68 -> 5933824
    float* qf    = w + 5933824;            // -> 6064896
    ushort* su   = (ushort*)(w + 6064896); // bf16 weight region
    ushort* WT1    = su;                   // 512*128   = 65536
    ushort* WTb    = su + 65536;           // 4*512*512 = 1048576
    ushort* WT7    = su + 1114112;         // 68*512    = 34816
    ushort* A16_1  = su + 1148928;         // 135*192   = 25920
    ushort* A16_B  = su + 1174848;         // 540*192   = 103680
    ushort* A16_7  = su + 1278528;         // 25920
    float* bnT   = w + 6717120;            // 10 * 69632 -> 7413440
    float* kf    = w + 7413440;            // 256*87*512 -> 18816704
    ushort* R2   = (ushort*)(w + 18816704);
    ushort* yT16  = R2;
    ushort* r1k16 = R2;                    // phase-A alias
    ushort* r1q16 = R2 + 11927552;
    ushort* R3   = (ushort*)(w + 27729600);
    ushort* hT16  = R3;
    ushort* pb16  = R3;                    // phase-A alias
    ushort* Wt1k  = R3 + 5013504;
    ushort* Wt1q  = R3 + 5439488;
    ushort* Wt2k  = R3 + 5865472;
    ushort* Wt2q  = R3 + 7176192;
    ushort* R4   = (ushort*)(w + 36642496);
    ushort* zN16  = R4;
    ushort* xT16  = R4;                    // alias (dead before zN16 written)
    ushort* z116  = R4 + 2367488;          // RP*80
    float* zpadf = w + 45555392;           // 128 f zero page
    const ushort* zpad = (const ushort*)zpadf;

    const int INF_RPB = 1 << 30;

    // ---- fused prep (one dispatch) ----
    prep_all<<<PB_DCT, 256, 0, stream>>>(
        poses, pb16, kw1, qw1, Wt1k, Wt1q, kw2, qw2, Wt2k, Wt2q,
        gc1_w, WT1, gcb_w, WTb, gc7_w, WT7,
        gc1_att, A16_1, gcb_att, A16_B, gc7_att, A16_7,
        bn1_g, bn1_b, gcb_g, gcb_beta, bnT, zpadf, dct);

    // ---- conv stack ----
    // conv1k: BM=128,BN=64; A-stream m-partitioned per XCD (mode 2): 182 m-blocks, Pc=23
    gemm2<128,64><<<dim3(1472, 1, 1), 256, 0, stream>>>(pb16, Wt1k, zpad, 23296, 512, 832,
        2, 8, 23, 91, 19584LL, 136LL, 0LL, 832LL, 0LL,
        (float*)nullptr, r1k16, 0LL, 512LL, 1LL, 1, nullptr, 0, nullptr, nullptr, 0, nullptr, nullptr);
    gemm2<128,128><<<dim3(4, 10, 1), 256, 0, stream>>>(pb16 + 110*136, Wt1q, zpad, 1280, 512, 832,
        0, 0, 0, 5, 19584LL, 136LL, 0LL, 832LL, 0LL,
        (float*)nullptr, r1q16, 0LL, 512LL, 1LL, 1, nullptr, 0, nullptr, nullptr, 0, nullptr, nullptr);
    // conv2k: BM=128,BN=64; mode 2: 174 m-blocks, Pc=22
    gemm2<128,64><<<dim3(1408, 1, 1), 256, 0, stream>>>(r1k16, Wt2k, zpad, 22272, 512, 2560,
        2, 8, 22, 87, 46592LL, 512LL, 0LL, 2560LL, 0LL,
        kf, (ushort*)nullptr, 0LL, 512LL, 1LL, 1, nullptr, 0, nullptr, nullptr, 0, nullptr, nullptr);
    gemm2<64,64><<<dim3(8, 4, 1), 256, 0, stream>>>(r1q16, Wt2q, zpad, 256, 512, 2560,
        0, 0, 0, INF_RPB, 0LL, 2560LL, 0LL, 2560LL, 0LL,
        qf, (ushort*)nullptr, 0LL, 512LL, 1LL, 1, nullptr, 0, nullptr, nullptr, 0, nullptr, nullptr);

    // ---- attention + x ----
    att_k<<<BATCH, 256, 0, stream>>>(kf, qf, att);
    weighted_k<<<dim3(DCTN, BATCH), 192, 0, stream>>>(poses, att, w34);
    build_x<<<(BATCH * NF * 68 + 255) / 256, 256, 0, stream>>>(poses, w34, dct, x32, xT16);

    // ---- gc1: mix then W(68->512) ----
    gemm2<64,64><<<dim3(3, 2, BATCH), 256, 0, stream>>>(xT16, A16_1, zpad, 68, 135, 192,
        0, 0, 0, INF_RPB, 0LL, (long long)RP, 136LL, 192LL, 0LL,
        (float*)nullptr, z116, 10880LL, 1LL, 80LL, 0, nullptr, 0, nullptr, nullptr, 0, nullptr, nullptr);
    // gc1 W: BM=128,BN=64; B-stream n-partitioned per XCD (mode 1): MBc=4, Pc=68
    gemm2<128,64><<<dim3(2176, 1, 1), 256, 0, stream>>>(WT1, z116, zpad, 512, RP, 128,
        1, 4, 68, INF_RPB, 0LL, 128LL, 0LL, 80LL, 0LL,
        (float*)nullptr, yT16, 0LL, (long long)RP, 1LL, 0, gc1_b, 1, bnT, bnT + 69632, 1, nullptr, nullptr);

    // ---- residual GCN blocks ----
    for (int L = 0; L < 4; L++) {
        const ushort* min = (L & 1) ? hT16 : yT16;
        gemm2<64,64><<<dim3(3, 8, BATCH), 256, 0, stream>>>(min, A16_B + L*25920, zpad, 512, 135, 192,
            0, 0, 0, INF_RPB, 0LL, (long long)RP, 136LL, 192LL, 0LL,
            (float*)nullptr, zN16, 69632LL, 1LL, 512LL, 0, nullptr, 0, nullptr, nullptr, 0, nullptr, nullptr);
        gemm2<128,64><<<dim3(2176, 1, 1), 256, 0, stream>>>(WTb + L*262144, zN16, zpad, 512, RP, 512,
            1, 4, 68, INF_RPB, 0LL, 512LL, 0LL, 512LL, 0LL,
            (float*)nullptr, (L & 1) ? yT16 : hT16, 0LL, (long long)RP, 1LL,
            0, gcb_b + L*512, 1, bnT + (1 + L) * 139264, bnT + (1 + L) * 139264 + 69632, 1,
            (L & 1) ? yT16 : (const ushort*)nullptr, nullptr);
    }

    // ---- gc7: mix then W(512->68) + bias + x residual ----
    gemm2<64,64><<<dim3(3, 8, BATCH), 256, 0, stream>>>(yT16, A16_7, zpad, 512, 135, 192,
        0, 0, 0, INF_RPB, 0LL, (long long)RP, 136LL, 192LL, 0LL,
        (float*)nullptr, zN16, 69632LL, 1LL, 512LL, 0, nullptr, 0, nullptr, nullptr, 0, nullptr, nullptr);
    // gc7 W: BM=64,BN=64; A-stream m-partitioned per XCD (mode 2): NBc=2, Pc=68
    gemm2<64,64><<<dim3(1088, 1, 1), 256, 0, stream>>>(zN16, WT7, zpad, RP, 68, 512,
        2, 2, 68, INF_RPB, 0LL, 512LL, 0LL, 512LL, 0LL,
        h32, (ushort*)nullptr, 0LL, 68LL, 1LL, 0, gc7_b, 2, nullptr, nullptr, 0, nullptr, x32);

    idct_out<<<(BATCH * OUTN * NF + 255) / 256, 256, 0, stream>>>(h32, dct, out);
}